// Round 7
// baseline (865.818 us; speedup 1.0000x reference)
//
#include <hip/hip_runtime.h>

#define EPSQ 1e-8f

typedef unsigned short u16;
typedef signed char i8;
typedef __attribute__((ext_vector_type(4))) int int4v;
typedef __attribute__((ext_vector_type(4))) unsigned int uint4v;

static constexpr int  Bn = 8, Cc = 128, Hh = 128, Ww = 128, HW = Hh * Ww; // 16384
static constexpr int  C4 = 512, CO = 256;
static constexpr long NX   = (long)Bn * Cc * HW;   // 16,777,216
static constexpr long NOUT = (long)Bn * CO * HW;   // 33,554,432

#define MFMAI8(a,b,c) __builtin_amdgcn_mfma_i32_16x16x64_i8(a,b,c,0,0,0)

__device__ __forceinline__ float ubits(unsigned u) { return __uint_as_float(u); }

// ---------------- reductions ----------------

__device__ __forceinline__ void block_max_atomic(float v, unsigned* slot) {
    #pragma unroll
    for (int off = 32; off; off >>= 1) v = fmaxf(v, __shfl_down(v, off));
    __shared__ float sm[8];
    int lane = threadIdx.x & 63, wid = threadIdx.x >> 6;
    if (lane == 0) sm[wid] = v;
    __syncthreads();
    if (threadIdx.x == 0) {
        float m = sm[0];
        int nw = (blockDim.x + 63) >> 6;
        for (int i = 1; i < nw; i++) m = fmaxf(m, sm[i]);
        if (m > __uint_as_float(*(volatile unsigned*)slot))
            atomicMax(slot, __float_as_uint(m));
    }
    __syncthreads();
}

// version with caller-provided LDS scratch
__device__ __forceinline__ void block_max_atomic2(float v, unsigned* slot, float* sm) {
    #pragma unroll
    for (int off = 32; off; off >>= 1) v = fmaxf(v, __shfl_down(v, off));
    int lane = threadIdx.x & 63, wid = threadIdx.x >> 6;
    __syncthreads();
    if (lane == 0) sm[wid] = v;
    __syncthreads();
    if (threadIdx.x == 0) {
        float m = sm[0];
        int nw = (blockDim.x + 63) >> 6;
        for (int i = 1; i < nw; i++) m = fmaxf(m, sm[i]);
        if (m > __uint_as_float(*(volatile unsigned*)slot))
            atomicMax(slot, __float_as_uint(m));
    }
}

// ---------------- absmax over big tensor ----------------

__global__ void absmax_kernel(const float* __restrict__ x, long n, unsigned* slot) {
    long i = (long)blockIdx.x * blockDim.x + threadIdx.x;
    long stride = (long)gridDim.x * blockDim.x;
    const float4* x4 = (const float4*)x;
    long n4 = n >> 2;
    float m = 0.f;
    for (long j = i; j < n4; j += stride) {
        float4 v = x4[j];
        m = fmaxf(m, fmaxf(fmaxf(fabsf(v.x), fabsf(v.y)), fmaxf(fabsf(v.z), fabsf(v.w))));
    }
    block_max_atomic(m, slot);
}

// ---------------- weight fake-quant ----------------
// mode 0: fp32 dequant to dstF.
// mode 1: i8 codes packed for 16x16x64 MFMA: [otile][kb(64)][lane][16], o=otile*16+(lane&15),
//         k=kb*64+(lane>>4)*16+e. If corr: corr[o] += code (pw2 shift correction).
// mode 2: 3x3 (K=128): [otile][tap][kb][lane][16]; corr[(tap/3)*256+o] += code.
struct QW { const float* src; float* dstF; i8* dstC; int n; int mode; int slot; int kdim; int* corr; };

__device__ __forceinline__ QW qw_select(const QW& q0, const QW& q1, const QW& q2, const QW& q3,
                                        const QW& q4, const QW& q5, const QW& q6, const QW& q7,
                                        const QW& q8, const QW& q9, int t) {
    switch (t) {
        case 0: return q0; case 1: return q1; case 2: return q2; case 3: return q3;
        case 4: return q4; case 5: return q5; case 6: return q6; case 7: return q7;
        case 8: return q8; default: return q9;
    }
}

__global__ void wabsmax_kernel(QW q0, QW q1, QW q2, QW q3, QW q4,
                               QW q5, QW q6, QW q7, QW q8, QW q9,
                               unsigned* __restrict__ scal) {
    QW q = qw_select(q0, q1, q2, q3, q4, q5, q6, q7, q8, q9, blockIdx.y);
    int i0 = blockIdx.x * blockDim.x + threadIdx.x;
    int str = gridDim.x * blockDim.x;
    float m = 0.f;
    for (int i = i0; i < q.n; i += str) m = fmaxf(m, fabsf(q.src[i]));
    block_max_atomic(m, scal + 16 + blockIdx.y);
}

__global__ void wquant_kernel(QW q0, QW q1, QW q2, QW q3, QW q4,
                              QW q5, QW q6, QW q7, QW q8, QW q9,
                              unsigned* __restrict__ scal) {
    QW q = qw_select(q0, q1, q2, q3, q4, q5, q6, q7, q8, q9, blockIdx.y);
    float s = fmaxf(ubits(scal[16 + blockIdx.y]), EPSQ) / 127.f;
    if (q.mode != 0 && blockIdx.x == 0 && threadIdx.x == 0) scal[q.slot] = __float_as_uint(s);
    int i0 = blockIdx.x * blockDim.x + threadIdx.x;
    int str = gridDim.x * blockDim.x;
    for (int i = i0; i < q.n; i += str) {
        float v = fminf(fmaxf(rintf(q.src[i] / s), -127.f), 127.f);
        int code = (int)v;
        if (q.mode == 0) q.dstF[i] = v * s;
        else if (q.mode == 1) {
            int o = i / q.kdim, k = i % q.kdim;
            int otile = o >> 4, r = o & 15, kb = k >> 6, qq = (k & 63) >> 4, e = k & 15;
            q.dstC[((otile * (q.kdim >> 6) + kb) * 64 + qq * 16 + r) * 16 + e] = (i8)code;
            if (q.corr) atomicAdd(&q.corr[o], code);
        } else {
            int o = i / 1152, rem = i % 1152, c = rem / 9, t = rem % 9;
            int otile = o >> 4, r = o & 15, kb = c >> 6, qq = (c & 63) >> 4, e = c & 15;
            q.dstC[(((otile * 9 + t) * 2 + kb) * 64 + qq * 16 + r) * 16 + e] = (i8)code;
            atomicAdd(&q.corr[(t / 3) * 256 + o], code);
        }
    }
}

// ---------------- depthwise 3x3 (pad 1), fp32 ----------------

__global__ void dwconv_kernel(const float* __restrict__ in, const float* __restrict__ wq,
                              const float* __restrict__ bq, float* __restrict__ out,
                              unsigned* mslot) {
    int bc = blockIdx.x;              // b*C + c
    int c  = bc & (Cc - 1);
    float w[9];
    #pragma unroll
    for (int k = 0; k < 9; k++) w[k] = wq[c * 9 + k];
    float bias = bq[c];
    const float* src = in + (long)bc * HW;
    float* dst = out + (long)bc * HW;
    int j  = threadIdx.x & (Ww - 1);
    int r2 = threadIdx.x >> 7;        // 0..1
    float mm = 0.f;
    #pragma unroll
    for (int rr = 0; rr < 4; rr++) {
        int i = blockIdx.y * 8 + rr * 2 + r2;
        float acc = 0.f;
        #pragma unroll
        for (int di = 0; di < 3; di++) {
            int ii = i + di - 1;
            if (ii < 0 || ii >= Hh) continue;
            #pragma unroll
            for (int dj = 0; dj < 3; dj++) {
                int jj = j + dj - 1;
                if (jj < 0 || jj >= Ww) continue;
                acc = fmaf(w[di * 3 + dj], src[ii * Ww + jj], acc);
            }
        }
        acc += bias;
        dst[i * Ww + j] = acc;
        mm = fmaxf(mm, fmaxf(acc, 0.f));
    }
    block_max_atomic(mm, mslot);
}

// ---------------- residual 1: r = fq(quant_relu(t)) + fq(x), fp32 out + max ----------------

__global__ void residual_kernel(const float4* __restrict__ t, const float4* __restrict__ xin,
                                float4* __restrict__ r, const unsigned* __restrict__ scal,
                                int mReluIdx, int mXIdx, unsigned* mOut) {
    float s1  = fmaxf(__uint_as_float(scal[mReluIdx]), EPSQ) / 255.f;
    float mh  = 255.f * s1;
    float s1b = fmaxf(mh, EPSQ) / 127.f;
    float sx  = fmaxf(__uint_as_float(scal[mXIdx]), EPSQ) / 127.f;
    long i0 = (long)blockIdx.x * blockDim.x + threadIdx.x;
    long str = (long)gridDim.x * blockDim.x;
    long n4 = NX >> 2;
    float mm = 0.f;
    for (long i = i0; i < n4; i += str) {
        float4 tv = t[i];
        float4 xv = xin[i];
        float o[4];
        float tc[4] = {tv.x, tv.y, tv.z, tv.w};
        float xc[4] = {xv.x, xv.y, xv.z, xv.w};
        #pragma unroll
        for (int k = 0; k < 4; k++) {
            float h  = fminf(rintf(fmaxf(tc[k], 0.f) / s1), 255.f) * s1;
            float hq = fminf(fmaxf(rintf(h / s1b), -127.f), 127.f) * s1b;
            float xq = fminf(fmaxf(rintf(xc[k] / sx), -127.f), 127.f) * sx;
            o[k] = hq + xq;
            mm = fmaxf(mm, fabsf(o[k]));
        }
        float4 ov = {o[0], o[1], o[2], o[3]};
        r[i] = ov;
    }
    if (mOut) block_max_atomic(mm, mOut);
}

// ---------------- residual 2: emit NHWC i8 code planes (j from dw2-path, i from r1) ----------------

__global__ __launch_bounds__(256) void residual2_codes_kernel(
    const float* __restrict__ t2, const float* __restrict__ r1,
    i8* __restrict__ jc, i8* __restrict__ ic, const unsigned* __restrict__ scal) {
    float s1  = fmaxf(ubits(scal[3]), EPSQ) / 255.f;
    float s1b = fmaxf(255.f * s1, EPSQ) / 127.f;
    float sx  = fmaxf(ubits(scal[2]), EPSQ) / 127.f;
    int b = blockIdx.x >> 8;
    long px0 = (long)(blockIdx.x & 255) * 64;
    __shared__ __align__(16) i8 lj[64 * 128];
    __shared__ __align__(16) i8 li[64 * 128];
    int px = threadIdx.x & 63, cq = threadIdx.x >> 6;
    for (int it = 0; it < 8; it++) {
        int cb = it * 16 + cq * 4;
        unsigned pj = 0, pi = 0;
        #pragma unroll
        for (int e = 0; e < 4; e++) {
            int c = cb + e;
            long g = ((long)b * Cc + c) * HW + px0 + px;
            float t = t2[g], x = r1[g];
            float hq = fminf(rintf(fmaxf(t, 0.f) / s1), 255.f) * s1;
            int j = (int)fminf(fmaxf(rintf(hq / s1b), -127.f), 127.f);
            int i = (int)fminf(fmaxf(rintf(x / sx), -127.f), 127.f);
            pj |= ((unsigned)(unsigned char)(i8)j) << (8 * e);
            pi |= ((unsigned)(unsigned char)(i8)i) << (8 * e);
        }
        int ad = (px * 128 + cb) ^ ((px & 7) << 4);
        *reinterpret_cast<int*>(lj + ad) = (int)pj;
        *reinterpret_cast<int*>(li + ad) = (int)pi;
    }
    __syncthreads();
    for (int s = threadIdx.x; s < 512; s += 256) {
        int px2 = s >> 3, sl = s & 7;
        int ad = (px2 * 128 + sl * 16) ^ ((px2 & 7) << 4);
        long dst = ((long)b * HW + px0 + px2) * 128 + sl * 16;
        *reinterpret_cast<uint4v*>(jc + dst) = *reinterpret_cast<uint4v*>(lj + ad);
        *reinterpret_cast<uint4v*>(ic + dst) = *reinterpret_cast<uint4v*>(li + ad);
    }
}

// ---------------- pointwise i8-MFMA GEMM over integer codes ----------------
// Block: 256 thr = 4 waves. Tile OB outputs x 64 px. K=64 per MFMA.
// MODE 0: relu max only. MODE 1: write quantized i8 codes (shifted -128) NHWC.
template<int K, int OB, bool DUAL, int MODE>
__global__ __launch_bounds__(256) void pwmfma_kernel(
    const i8* __restrict__ bc0, const i8* __restrict__ bc1,
    const i8* __restrict__ wc, const float* __restrict__ bias,
    i8* __restrict__ outc, const unsigned* __restrict__ scal,
    const int* __restrict__ corrI,
    int O_total, int sInSlot, int sWSlot, int sOutSlot, unsigned* mslot) {

    constexpr int F = OB / 64;                    // o-frags (of 16) per wave
    constexpr int KB = K / 64;
    constexpr int LSZ = (DUAL ? 2 : 1) * 64 * K;
    __shared__ __align__(16) i8 lds[LSZ];
    int lane = threadIdx.x & 63, wv = threadIdx.x >> 6;
    int lane15 = lane & 15;
    int b = blockIdx.x >> 8;
    long px0 = (long)(blockIdx.x & 255) * 64;
    long pixbase = (long)b * HW + px0;
    int oB = blockIdx.y * OB;
    int oW = wv * (OB / 4);

    for (int s = threadIdx.x; s < 4 * K; s += 256) {        // 64 px * K/16 chunks
        int px = s / (K / 16), cs = s % (K / 16);
        long gsrc = (pixbase + px) * K + cs * 16;
        int addr = (px * K + cs * 16) ^ ((px & 7) << 4);
        *reinterpret_cast<uint4v*>(lds + addr) = *reinterpret_cast<const uint4v*>(bc0 + gsrc);
        if (DUAL)
            *reinterpret_cast<uint4v*>(lds + 64 * K + addr) =
                *reinterpret_cast<const uint4v*>(bc1 + gsrc);
    }
    __syncthreads();

    const int4v z4 = {0, 0, 0, 0};
    int4v accA[F][4], accB[F][4];
    #pragma unroll
    for (int i = 0; i < F; i++)
        #pragma unroll
        for (int j = 0; j < 4; j++) { accA[i][j] = z4; accB[i][j] = z4; }

    const i8* wpack = wc + ((long)((oB + oW) >> 4) * KB) * 1024 + lane * 16;

    #pragma unroll
    for (int kb = 0; kb < KB; kb++) {
        int4v a[F];
        #pragma unroll
        for (int f = 0; f < F; f++)
            a[f] = *reinterpret_cast<const int4v*>(wpack + ((long)f * KB + kb) * 1024);
        #pragma unroll
        for (int fn = 0; fn < 4; fn++) {
            int col = fn * 16 + lane15;
            int ad = (col * K + kb * 64 + (lane >> 4) * 16) ^ ((col & 7) << 4);
            int4v b0 = *reinterpret_cast<const int4v*>(lds + ad);
            #pragma unroll
            for (int f = 0; f < F; f++) accA[f][fn] = MFMAI8(a[f], b0, accA[f][fn]);
            if (DUAL) {
                int4v b1 = *reinterpret_cast<const int4v*>(lds + 64 * K + ad);
                #pragma unroll
                for (int f = 0; f < F; f++) accB[f][fn] = MFMAI8(a[f], b1, accB[f][fn]);
            }
        }
    }

    float sW = ubits(scal[sWSlot]);
    float sA, sB_;
    if (DUAL) {
        float s1 = fmaxf(ubits(scal[3]), EPSQ) / 255.f;
        sA  = fmaxf(255.f * s1, EPSQ) / 127.f;     // s1b (j codes)
        sB_ = fmaxf(ubits(scal[2]), EPSQ) / 127.f; // sx  (i codes)
    } else {
        sA = fmaxf(ubits(scal[sInSlot]), EPSQ) / 255.f;
        sB_ = 0.f;
    }

    if (MODE == 0) {
        float mm = 0.f;
        #pragma unroll
        for (int f = 0; f < F; f++)
        #pragma unroll
        for (int fn = 0; fn < 4; fn++)
        #pragma unroll
        for (int r = 0; r < 4; r++) {
            int o = oB + oW + f * 16 + (lane >> 4) * 4 + r;
            float av;
            if (DUAL) av = sA * (float)accA[f][fn][r] + sB_ * (float)accB[f][fn][r];
            else      av = sA * (float)(accA[f][fn][r] + (corrI[o] << 7));
            float v = fmaxf(sW * av + bias[o], 0.f);
            mm = fmaxf(mm, v);
        }
        block_max_atomic2(mm, mslot, reinterpret_cast<float*>(lds));
    } else {
        float sOut = fmaxf(ubits(scal[sOutSlot]), EPSQ) / 255.f;
        __syncthreads();
        #pragma unroll
        for (int f = 0; f < F; f++)
        #pragma unroll
        for (int fn = 0; fn < 4; fn++) {
            int orow0 = oW + f * 16 + (lane >> 4) * 4;
            unsigned pk = 0;
            #pragma unroll
            for (int r = 0; r < 4; r++) {
                int o = oB + orow0 + r;
                float av;
                if (DUAL) av = sA * (float)accA[f][fn][r] + sB_ * (float)accB[f][fn][r];
                else      av = sA * (float)(accA[f][fn][r] + (corrI[o] << 7));
                float v = fmaxf(sW * av + bias[o], 0.f);
                int code = (int)fminf(rintf(v / sOut), 255.f) - 128;   // shifted storage
                pk |= ((unsigned)(unsigned char)(i8)code) << (8 * r);
            }
            int pxl = fn * 16 + lane15;
            int ad = (pxl * OB + orow0) ^ ((pxl & 7) << 4);
            *reinterpret_cast<int*>(lds + ad) = (int)pk;
        }
        __syncthreads();
        constexpr int CH = OB / 16;       // 16B chunks per px row
        for (int s = threadIdx.x; s < 64 * CH; s += 256) {
            int px = s / CH, sl = s % CH;
            int ad = (px * OB + sl * 16) ^ ((px & 7) << 4);
            *reinterpret_cast<uint4v*>(outc + (pixbase + px) * O_total + oB + sl * 16) =
                *reinterpret_cast<uint4v*>(lds + ad);
        }
    }
}

// ---------------- 3x3 conv 128->256 i8-MFMA, fp32 NCHW out + max ----------------
// Input codes stored shifted (k-128); OOB cols stage 0x80 (= shifted zero);
// per-o integer correction 128*sum(W) per executed tap-row restores exactness.

__global__ __launch_bounds__(256) void conv3x3_mfma_kernel(
    const i8* __restrict__ xc,    // NHWC shifted codes [B*HW][128]
    const i8* __restrict__ wc,    // packed [16][9][2][64][16]
    const float* __restrict__ bias, float* __restrict__ out,
    const unsigned* __restrict__ scal, const int* __restrict__ corrU,
    unsigned* mslot) {

    __shared__ __align__(16) i8 lds[3 * 66 * 128];
    int lane = threadIdx.x & 63, wv = threadIdx.x >> 6;
    int lane15 = lane & 15;
    int bx = blockIdx.x;
    int b = bx >> 8, h = (bx >> 1) & 127, wseg = bx & 1;
    int oW = wv * 64;

    // stage 3 rows x 66 cols x 128 ch (i8); OOB cols = 0x80 (shifted zero)
    for (int s = threadIdx.x; s < 3 * 66 * 8; s += 256) {
        int row = s / (66 * 8), rem = s % (66 * 8), col = rem >> 3, sl = rem & 7;
        int hh = h + row - 1;
        if (hh < 0 || hh > 127) continue;      // row's taps skipped entirely
        int wgl = wseg * 64 + col - 1;
        uint4v v = {0x80808080u, 0x80808080u, 0x80808080u, 0x80808080u};
        if (wgl >= 0 && wgl <= 127) {
            long pix = (long)b * HW + (long)hh * 128 + wgl;
            v = *reinterpret_cast<const uint4v*>(xc + pix * 128 + sl * 16);
        }
        int addr = ((row * 66 + col) * 128 + sl * 16) ^ ((col & 7) << 4);
        *reinterpret_cast<uint4v*>(lds + addr) = v;
    }
    __syncthreads();

    const int4v z4 = {0, 0, 0, 0};
    int4v acc[4][4];
    #pragma unroll
    for (int i = 0; i < 4; i++)
        #pragma unroll
        for (int j = 0; j < 4; j++) acc[i][j] = z4;

    const i8* wpack = wc + (long)(wv * 4) * 18 * 1024 + lane * 16;  // otile0 = wv*4
    for (int di = 0; di < 3; di++) {
        int hh = h + di - 1;
        if (hh < 0 || hh > 127) continue;      // block-uniform
        for (int dj = 0; dj < 3; dj++) {
            int tap = di * 3 + dj;
            #pragma unroll
            for (int kb = 0; kb < 2; kb++) {
                int4v a[4];
                #pragma unroll
                for (int f = 0; f < 4; f++)
                    a[f] = *reinterpret_cast<const int4v*>(
                        wpack + ((long)(f * 9 + tap) * 2 + kb) * 1024);
                int4v bb[4];
                #pragma unroll
                for (int fn = 0; fn < 4; fn++) {
                    int col = fn * 16 + lane15 + dj;
                    bb[fn] = *reinterpret_cast<const int4v*>(lds +
                        (((di * 66 + col) * 128 + kb * 64 + (lane >> 4) * 16) ^ ((col & 7) << 4)));
                }
                #pragma unroll
                for (int f = 0; f < 4; f++)
                    #pragma unroll
                    for (int fn = 0; fn < 4; fn++)
                        acc[f][fn] = MFMAI8(a[f], bb[fn], acc[f][fn]);
            }
        }
    }

    float s5 = fmaxf(ubits(scal[5]), EPSQ) / 255.f;
    float sc = ubits(scal[10]) * s5;
    float mm = 0.f;
    #pragma unroll
    for (int f = 0; f < 4; f++)
    #pragma unroll
    for (int r = 0; r < 4; r++) {
        int o = oW + f * 16 + (lane >> 4) * 4 + r;
        int csum = corrU[256 + o];
        if (h > 0)   csum += corrU[o];
        if (h < 127) csum += corrU[512 + o];
        #pragma unroll
        for (int fn = 0; fn < 4; fn++) {
            int px = wseg * 64 + fn * 16 + lane15;
            int ai = acc[f][fn][r] + (csum << 7);
            float v = fmaxf(sc * (float)ai + bias[o], 0.f);
            mm = fmaxf(mm, v);
            out[((long)(b * CO + o)) * HW + h * 128 + px] = v;
        }
    }
    block_max_atomic2(mm, mslot, reinterpret_cast<float*>(lds));
}

// ---------------- in-place quant of a relu'd tensor (255 levels) ----------------

__global__ void quant_inplace_kernel(float4* __restrict__ p, long n4,
                                     const unsigned* __restrict__ scal, int idx) {
    float s = fmaxf(__uint_as_float(scal[idx]), EPSQ) / 255.f;
    long i0 = (long)blockIdx.x * blockDim.x + threadIdx.x;
    long str = (long)gridDim.x * blockDim.x;
    for (long i = i0; i < n4; i += str) {
        float4 v = p[i];
        v.x = fminf(rintf(v.x / s), 255.f) * s;
        v.y = fminf(rintf(v.y / s), 255.f) * s;
        v.z = fminf(rintf(v.z / s), 255.f) * s;
        v.w = fminf(rintf(v.w / s), 255.f) * s;
        p[i] = v;
    }
}

// ---------------- launch ----------------

extern "C" void kernel_launch(void* const* d_in, const int* in_sizes, int n_in,
                              void* d_out, int out_size, void* d_ws, size_t ws_size,
                              hipStream_t stream) {
    (void)in_sizes; (void)n_in; (void)out_size; (void)ws_size;
    const float* x     = (const float*)d_in[0];
    const float* dw1_w = (const float*)d_in[1];
    const float* dw1_b = (const float*)d_in[2];
    const float* dw2_w = (const float*)d_in[3];
    const float* dw2_b = (const float*)d_in[4];
    const float* pw1_w = (const float*)d_in[5];
    const float* pw1_b = (const float*)d_in[6];
    const float* pw2_w = (const float*)d_in[7];
    const float* pw2_b = (const float*)d_in[8];
    const float* up_w  = (const float*)d_in[9];
    const float* up_b  = (const float*)d_in[10];
    float* out = (float*)d_out;
    float* ws  = (float*)d_ws;

    // ws layout (float units):
    // [0, NX)          Abuf fp32          (later: p1codes i8, NP1 bytes = NX*4 B exact fit)
    // [NX, 2NX)        Bbuf fp32
    // [2NX, 2NX+NX/4)  jcode i8 NX bytes  (later: p2codes i8 NX bytes)
    // [2NX+NX/4, 2NX+NX/2) icode i8 NX bytes
    // [3NX, ...)       weight area + scal + corr
    float* Abuf = ws;
    float* Bbuf = ws + NX;
    i8*    jcode   = (i8*)(ws + 2 * NX);
    i8*    icode   = jcode + NX;
    i8*    p1codes = (i8*)ws;
    i8*    p2codes = (i8*)(ws + 2 * NX);

    float* wbase  = ws + 3 * NX;
    float* wq_dw1 = wbase;          float* bq_dw1 = wbase + 1152;
    float* wq_dw2 = wbase + 1280;   float* bq_dw2 = wbase + 2432;
    float* bq_pw1 = wbase + 2560;
    float* bq_pw2 = wbase + 3072;
    float* bq_up  = wbase + 3200;
    i8*    wc_pw1 = (i8*)(wbase + 3456);    // 65536 B
    i8*    wc_pw2 = (i8*)(wbase + 19840);   // 65536 B
    i8*    wc_up  = (i8*)(wbase + 36224);   // 294912 B
    unsigned* scal = (unsigned*)(wbase + 109952);
    int*   corrU  = (int*)(wbase + 109984);   // [3][256]
    int*   corrP2 = (int*)(wbase + 110752);   // [128]
    // scal slots: 0 SX | 1 M1 | 2 MR1 | 3 M2 | 4 M3(pw1 relu) | 5 M4(pw2 relu)
    //             6 M5(up relu) | 8 sW_pw1 | 9 sW_pw2 | 10 sW_up | 16..25 weight absmax

    (void)hipMemsetAsync(scal, 0, (32 + 768 + 128) * sizeof(unsigned), stream);

    QW q0{dw1_w, wq_dw1, nullptr, 1152, 0, 0, 9, nullptr},
       q1{dw1_b, bq_dw1, nullptr, 128, 0, 0, 1, nullptr},
       q2{dw2_w, wq_dw2, nullptr, 1152, 0, 0, 9, nullptr},
       q3{dw2_b, bq_dw2, nullptr, 128, 0, 0, 1, nullptr},
       q4{pw1_w, nullptr, wc_pw1, 65536, 1, 8, 128, nullptr},
       q5{pw1_b, bq_pw1, nullptr, 512, 0, 0, 1, nullptr},
       q6{pw2_w, nullptr, wc_pw2, 65536, 1, 9, 512, corrP2},
       q7{pw2_b, bq_pw2, nullptr, 128, 0, 0, 1, nullptr},
       q8{up_w, nullptr, wc_up, 294912, 2, 10, 128, corrU},
       q9{up_b, bq_up, nullptr, 256, 0, 0, 1, nullptr};
    wabsmax_kernel<<<dim3(32, 10), 256, 0, stream>>>(q0, q1, q2, q3, q4, q5, q6, q7, q8, q9, scal);
    wquant_kernel<<<dim3(32, 10), 256, 0, stream>>>(q0, q1, q2, q3, q4, q5, q6, q7, q8, q9, scal);

    absmax_kernel<<<2048, 256, 0, stream>>>(x, NX, scal + 0);

    // residual block 1 (fp32 path)
    dwconv_kernel<<<dim3(Bn * Cc, Hh / 8), 256, 0, stream>>>(x, wq_dw1, bq_dw1, Abuf, scal + 1);
    residual_kernel<<<4096, 256, 0, stream>>>((const float4*)Abuf, (const float4*)x,
                                              (float4*)Bbuf, scal, 1, 0, scal + 2);
    // residual block 2 -> i8 NHWC code planes
    dwconv_kernel<<<dim3(Bn * Cc, Hh / 8), 256, 0, stream>>>(Bbuf, wq_dw2, bq_dw2, Abuf, scal + 3);
    residual2_codes_kernel<<<2048, 256, 0, stream>>>(Abuf, Bbuf, jcode, icode, scal);

    // pw1 (dual-plane exact GEMM): pass1 max -> slot4, pass2 shifted codes -> p1codes
    pwmfma_kernel<128, 256, true, 0><<<dim3(2048, 2), 256, 0, stream>>>(
        jcode, icode, wc_pw1, bq_pw1, nullptr, scal, nullptr, C4, 0, 8, 0, scal + 4);
    pwmfma_kernel<128, 256, true, 1><<<dim3(2048, 2), 256, 0, stream>>>(
        jcode, icode, wc_pw1, bq_pw1, p1codes, scal, nullptr, C4, 0, 8, 4, nullptr);

    // pw2: shifted input (corrP2), pass1 max -> slot5, pass2 shifted codes -> p2codes
    pwmfma_kernel<512, 128, false, 0><<<dim3(2048, 1), 256, 0, stream>>>(
        p1codes, nullptr, wc_pw2, bq_pw2, nullptr, scal, corrP2, Cc, 4, 9, 0, scal + 5);
    pwmfma_kernel<512, 128, false, 1><<<dim3(2048, 1), 256, 0, stream>>>(
        p1codes, nullptr, wc_pw2, bq_pw2, p2codes, scal, corrP2, Cc, 4, 9, 5, nullptr);

    // up 3x3 -> d_out fp32 + max slot6, then final quant in place
    conv3x3_mfma_kernel<<<2048, 256, 0, stream>>>(p2codes, wc_up, bq_up, out, scal, corrU, scal + 6);
    quant_inplace_kernel<<<4096, 256, 0, stream>>>((float4*)out, NOUT / 4, scal, 6);
}

// Round 8
// 571.431 us; speedup vs baseline: 1.5152x; 1.5152x over previous
//
#include <hip/hip_runtime.h>

#define EPSQ 1e-8f

typedef unsigned short u16;
typedef signed char i8;
typedef __attribute__((ext_vector_type(4))) int int4v;
typedef __attribute__((ext_vector_type(4))) unsigned int uint4v;

static constexpr int  Bn = 8, Cc = 128, Hh = 128, Ww = 128, HW = Hh * Ww; // 16384
static constexpr int  C4 = 512, CO = 256;
static constexpr long NX   = (long)Bn * Cc * HW;   // 16,777,216
static constexpr long NOUT = (long)Bn * CO * HW;   // 33,554,432

#define MFMAI8(a,b,c) __builtin_amdgcn_mfma_i32_16x16x64_i8(a,b,c,0,0,0)

__device__ __forceinline__ float ubits(unsigned u) { return __uint_as_float(u); }

// ---------------- reductions ----------------

__device__ __forceinline__ void block_max_atomic(float v, unsigned* slot) {
    #pragma unroll
    for (int off = 32; off; off >>= 1) v = fmaxf(v, __shfl_down(v, off));
    __shared__ float sm[8];
    int lane = threadIdx.x & 63, wid = threadIdx.x >> 6;
    if (lane == 0) sm[wid] = v;
    __syncthreads();
    if (threadIdx.x == 0) {
        float m = sm[0];
        int nw = (blockDim.x + 63) >> 6;
        for (int i = 1; i < nw; i++) m = fmaxf(m, sm[i]);
        if (m > __uint_as_float(*(volatile unsigned*)slot))
            atomicMax(slot, __float_as_uint(m));
    }
    __syncthreads();
}

// version with caller-provided LDS scratch
__device__ __forceinline__ void block_max_atomic2(float v, unsigned* slot, float* sm) {
    #pragma unroll
    for (int off = 32; off; off >>= 1) v = fmaxf(v, __shfl_down(v, off));
    int lane = threadIdx.x & 63, wid = threadIdx.x >> 6;
    __syncthreads();
    if (lane == 0) sm[wid] = v;
    __syncthreads();
    if (threadIdx.x == 0) {
        float m = sm[0];
        int nw = (blockDim.x + 63) >> 6;
        for (int i = 1; i < nw; i++) m = fmaxf(m, sm[i]);
        if (m > __uint_as_float(*(volatile unsigned*)slot))
            atomicMax(slot, __float_as_uint(m));
    }
}

// ---------------- absmax over big tensor ----------------

__global__ void absmax_kernel(const float* __restrict__ x, long n, unsigned* slot) {
    long i = (long)blockIdx.x * blockDim.x + threadIdx.x;
    long stride = (long)gridDim.x * blockDim.x;
    const float4* x4 = (const float4*)x;
    long n4 = n >> 2;
    float m = 0.f;
    for (long j = i; j < n4; j += stride) {
        float4 v = x4[j];
        m = fmaxf(m, fmaxf(fmaxf(fabsf(v.x), fabsf(v.y)), fmaxf(fabsf(v.z), fabsf(v.w))));
    }
    block_max_atomic(m, slot);
}

// ---------------- weight fake-quant ----------------
// mode 0: fp32 dequant to dstF.
// mode 1: i8 codes packed for 16x16x64 MFMA: [otile][kb(64)][lane][16], o=otile*16+(lane&15),
//         k=kb*64+(lane>>4)*16+e.
// mode 2: 3x3 (K=128): [otile][tap][kb][lane][16].
struct QW { const float* src; float* dstF; i8* dstC; int n; int mode; int slot; int kdim; };

__device__ __forceinline__ QW qw_select(const QW& q0, const QW& q1, const QW& q2, const QW& q3,
                                        const QW& q4, const QW& q5, const QW& q6, const QW& q7,
                                        const QW& q8, const QW& q9, int t) {
    switch (t) {
        case 0: return q0; case 1: return q1; case 2: return q2; case 3: return q3;
        case 4: return q4; case 5: return q5; case 6: return q6; case 7: return q7;
        case 8: return q8; default: return q9;
    }
}

__global__ void wabsmax_kernel(QW q0, QW q1, QW q2, QW q3, QW q4,
                               QW q5, QW q6, QW q7, QW q8, QW q9,
                               unsigned* __restrict__ scal) {
    QW q = qw_select(q0, q1, q2, q3, q4, q5, q6, q7, q8, q9, blockIdx.y);
    int i0 = blockIdx.x * blockDim.x + threadIdx.x;
    int str = gridDim.x * blockDim.x;
    float m = 0.f;
    for (int i = i0; i < q.n; i += str) m = fmaxf(m, fabsf(q.src[i]));
    block_max_atomic(m, scal + 16 + blockIdx.y);
}

__global__ void wquant_kernel(QW q0, QW q1, QW q2, QW q3, QW q4,
                              QW q5, QW q6, QW q7, QW q8, QW q9,
                              unsigned* __restrict__ scal) {
    QW q = qw_select(q0, q1, q2, q3, q4, q5, q6, q7, q8, q9, blockIdx.y);
    float s = fmaxf(ubits(scal[16 + blockIdx.y]), EPSQ) / 127.f;
    if (q.mode != 0 && blockIdx.x == 0 && threadIdx.x == 0) scal[q.slot] = __float_as_uint(s);
    int i0 = blockIdx.x * blockDim.x + threadIdx.x;
    int str = gridDim.x * blockDim.x;
    for (int i = i0; i < q.n; i += str) {
        float v = fminf(fmaxf(rintf(q.src[i] / s), -127.f), 127.f);
        int code = (int)v;
        if (q.mode == 0) q.dstF[i] = v * s;
        else if (q.mode == 1) {
            int o = i / q.kdim, k = i % q.kdim;
            int otile = o >> 4, r = o & 15, kb = k >> 6, qq = (k & 63) >> 4, e = k & 15;
            q.dstC[((otile * (q.kdim >> 6) + kb) * 64 + qq * 16 + r) * 16 + e] = (i8)code;
        } else {
            int o = i / 1152, rem = i % 1152, c = rem / 9, t = rem % 9;
            int otile = o >> 4, r = o & 15, kb = c >> 6, qq = (c & 63) >> 4, e = c & 15;
            q.dstC[(((otile * 9 + t) * 2 + kb) * 64 + qq * 16 + r) * 16 + e] = (i8)code;
        }
    }
}

// ---------------- shift-correction sums (atomic-free, 1 wave per output ch) ----------------
// y==0: corrP2[o] = sum_k code(pw2_w[o][k]),            o in [0,128)
// y==1: corrU[row*256+o] = sum_{c,dj} code(up_w[o][c][row*3+dj]), o in [0,256)

__global__ void corr_kernel(const float* __restrict__ pw2_w, const float* __restrict__ up_w,
                            const unsigned* __restrict__ scal,
                            int* __restrict__ corrP2, int* __restrict__ corrU) {
    int lane = threadIdx.x;           // 64 threads
    if (blockIdx.y == 0) {
        int o = blockIdx.x;
        if (o >= 128) return;
        float s = fmaxf(ubits(scal[16 + 6]), EPSQ) / 127.f;
        int sum = 0;
        for (int k = lane; k < 512; k += 64)
            sum += (int)fminf(fmaxf(rintf(pw2_w[o * 512 + k] / s), -127.f), 127.f);
        #pragma unroll
        for (int off = 32; off; off >>= 1) sum += __shfl_down(sum, off);
        if (lane == 0) corrP2[o] = sum;
    } else {
        int o = blockIdx.x;
        float s = fmaxf(ubits(scal[16 + 8]), EPSQ) / 127.f;
        int sum[3] = {0, 0, 0};
        for (int i = lane; i < 1152; i += 64) {
            int t = i % 9;
            int code = (int)fminf(fmaxf(rintf(up_w[o * 1152 + i] / s), -127.f), 127.f);
            sum[t / 3] += code;
        }
        #pragma unroll
        for (int r = 0; r < 3; r++) {
            int v = sum[r];
            #pragma unroll
            for (int off = 32; off; off >>= 1) v += __shfl_down(v, off);
            if (lane == 0) corrU[r * 256 + o] = v;
        }
    }
}

// ---------------- depthwise 3x3 (pad 1), fp32 ----------------

__global__ void dwconv_kernel(const float* __restrict__ in, const float* __restrict__ wq,
                              const float* __restrict__ bq, float* __restrict__ out,
                              unsigned* mslot) {
    int bc = blockIdx.x;              // b*C + c
    int c  = bc & (Cc - 1);
    float w[9];
    #pragma unroll
    for (int k = 0; k < 9; k++) w[k] = wq[c * 9 + k];
    float bias = bq[c];
    const float* src = in + (long)bc * HW;
    float* dst = out + (long)bc * HW;
    int j  = threadIdx.x & (Ww - 1);
    int r2 = threadIdx.x >> 7;        // 0..1
    float mm = 0.f;
    #pragma unroll
    for (int rr = 0; rr < 4; rr++) {
        int i = blockIdx.y * 8 + rr * 2 + r2;
        float acc = 0.f;
        #pragma unroll
        for (int di = 0; di < 3; di++) {
            int ii = i + di - 1;
            if (ii < 0 || ii >= Hh) continue;
            #pragma unroll
            for (int dj = 0; dj < 3; dj++) {
                int jj = j + dj - 1;
                if (jj < 0 || jj >= Ww) continue;
                acc = fmaf(w[di * 3 + dj], src[ii * Ww + jj], acc);
            }
        }
        acc += bias;
        dst[i * Ww + j] = acc;
        mm = fmaxf(mm, fmaxf(acc, 0.f));
    }
    block_max_atomic(mm, mslot);
}

// ---------------- residual 1: r = fq(quant_relu(t)) + fq(x), fp32 out + max ----------------

__global__ void residual_kernel(const float4* __restrict__ t, const float4* __restrict__ xin,
                                float4* __restrict__ r, const unsigned* __restrict__ scal,
                                int mReluIdx, int mXIdx, unsigned* mOut) {
    float s1  = fmaxf(__uint_as_float(scal[mReluIdx]), EPSQ) / 255.f;
    float mh  = 255.f * s1;
    float s1b = fmaxf(mh, EPSQ) / 127.f;
    float sx  = fmaxf(__uint_as_float(scal[mXIdx]), EPSQ) / 127.f;
    long i0 = (long)blockIdx.x * blockDim.x + threadIdx.x;
    long str = (long)gridDim.x * blockDim.x;
    long n4 = NX >> 2;
    float mm = 0.f;
    for (long i = i0; i < n4; i += str) {
        float4 tv = t[i];
        float4 xv = xin[i];
        float o[4];
        float tc[4] = {tv.x, tv.y, tv.z, tv.w};
        float xc[4] = {xv.x, xv.y, xv.z, xv.w};
        #pragma unroll
        for (int k = 0; k < 4; k++) {
            float h  = fminf(rintf(fmaxf(tc[k], 0.f) / s1), 255.f) * s1;
            float hq = fminf(fmaxf(rintf(h / s1b), -127.f), 127.f) * s1b;
            float xq = fminf(fmaxf(rintf(xc[k] / sx), -127.f), 127.f) * sx;
            o[k] = hq + xq;
            mm = fmaxf(mm, fabsf(o[k]));
        }
        float4 ov = {o[0], o[1], o[2], o[3]};
        r[i] = ov;
    }
    if (mOut) block_max_atomic(mm, mOut);
}

// ---------------- residual 2: emit NHWC i8 code planes (j from dw2-path, i from r1) ----------------

__global__ __launch_bounds__(256) void residual2_codes_kernel(
    const float* __restrict__ t2, const float* __restrict__ r1,
    i8* __restrict__ jc, i8* __restrict__ ic, const unsigned* __restrict__ scal) {
    float s1  = fmaxf(ubits(scal[3]), EPSQ) / 255.f;
    float s1b = fmaxf(255.f * s1, EPSQ) / 127.f;
    float sx  = fmaxf(ubits(scal[2]), EPSQ) / 127.f;
    int b = blockIdx.x >> 8;
    long px0 = (long)(blockIdx.x & 255) * 64;
    __shared__ __align__(16) i8 lj[64 * 128];
    __shared__ __align__(16) i8 li[64 * 128];
    int px = threadIdx.x & 63, cq = threadIdx.x >> 6;
    for (int it = 0; it < 8; it++) {
        int cb = it * 16 + cq * 4;
        unsigned pj = 0, pi = 0;
        #pragma unroll
        for (int e = 0; e < 4; e++) {
            int c = cb + e;
            long g = ((long)b * Cc + c) * HW + px0 + px;
            float t = t2[g], x = r1[g];
            float hq = fminf(rintf(fmaxf(t, 0.f) / s1), 255.f) * s1;
            int j = (int)fminf(fmaxf(rintf(hq / s1b), -127.f), 127.f);
            int i = (int)fminf(fmaxf(rintf(x / sx), -127.f), 127.f);
            pj |= ((unsigned)(unsigned char)(i8)j) << (8 * e);
            pi |= ((unsigned)(unsigned char)(i8)i) << (8 * e);
        }
        int ad = (px * 128 + cb) ^ ((px & 7) << 4);
        *reinterpret_cast<int*>(lj + ad) = (int)pj;
        *reinterpret_cast<int*>(li + ad) = (int)pi;
    }
    __syncthreads();
    for (int s = threadIdx.x; s < 512; s += 256) {
        int px2 = s >> 3, sl = s & 7;
        int ad = (px2 * 128 + sl * 16) ^ ((px2 & 7) << 4);
        long dst = ((long)b * HW + px0 + px2) * 128 + sl * 16;
        *reinterpret_cast<uint4v*>(jc + dst) = *reinterpret_cast<uint4v*>(lj + ad);
        *reinterpret_cast<uint4v*>(ic + dst) = *reinterpret_cast<uint4v*>(li + ad);
    }
}

// ---------------- pointwise i8-MFMA GEMM over integer codes ----------------
// Block: 256 thr = 4 waves. Tile OB outputs x 64 px. K=64 per MFMA.
// MODE 0: relu max only. MODE 1: write quantized i8 codes (shifted -128) NHWC.
template<int K, int OB, bool DUAL, int MODE>
__global__ __launch_bounds__(256) void pwmfma_kernel(
    const i8* __restrict__ bc0, const i8* __restrict__ bc1,
    const i8* __restrict__ wc, const float* __restrict__ bias,
    i8* __restrict__ outc, const unsigned* __restrict__ scal,
    const int* __restrict__ corrI,
    int O_total, int sInSlot, int sWSlot, int sOutSlot, unsigned* mslot) {

    constexpr int F = OB / 64;                    // o-frags (of 16) per wave
    constexpr int KB = K / 64;
    constexpr int LSZ = (DUAL ? 2 : 1) * 64 * K;
    __shared__ __align__(16) i8 lds[LSZ];
    int lane = threadIdx.x & 63, wv = threadIdx.x >> 6;
    int lane15 = lane & 15;
    int b = blockIdx.x >> 8;
    long px0 = (long)(blockIdx.x & 255) * 64;
    long pixbase = (long)b * HW + px0;
    int oB = blockIdx.y * OB;
    int oW = wv * (OB / 4);

    for (int s = threadIdx.x; s < 4 * K; s += 256) {        // 64 px * K/16 chunks
        int px = s / (K / 16), cs = s % (K / 16);
        long gsrc = (pixbase + px) * K + cs * 16;
        int addr = (px * K + cs * 16) ^ ((px & 7) << 4);
        *reinterpret_cast<uint4v*>(lds + addr) = *reinterpret_cast<const uint4v*>(bc0 + gsrc);
        if (DUAL)
            *reinterpret_cast<uint4v*>(lds + 64 * K + addr) =
                *reinterpret_cast<const uint4v*>(bc1 + gsrc);
    }
    __syncthreads();

    const int4v z4 = {0, 0, 0, 0};
    int4v accA[F][4], accB[F][4];
    #pragma unroll
    for (int i = 0; i < F; i++)
        #pragma unroll
        for (int j = 0; j < 4; j++) { accA[i][j] = z4; accB[i][j] = z4; }

    const i8* wpack = wc + ((long)((oB + oW) >> 4) * KB) * 1024 + lane * 16;

    #pragma unroll
    for (int kb = 0; kb < KB; kb++) {
        int4v a[F];
        #pragma unroll
        for (int f = 0; f < F; f++)
            a[f] = *reinterpret_cast<const int4v*>(wpack + ((long)f * KB + kb) * 1024);
        #pragma unroll
        for (int fn = 0; fn < 4; fn++) {
            int col = fn * 16 + lane15;
            int ad = (col * K + kb * 64 + (lane >> 4) * 16) ^ ((col & 7) << 4);
            int4v b0 = *reinterpret_cast<const int4v*>(lds + ad);
            #pragma unroll
            for (int f = 0; f < F; f++) accA[f][fn] = MFMAI8(a[f], b0, accA[f][fn]);
            if (DUAL) {
                int4v b1 = *reinterpret_cast<const int4v*>(lds + 64 * K + ad);
                #pragma unroll
                for (int f = 0; f < F; f++) accB[f][fn] = MFMAI8(a[f], b1, accB[f][fn]);
            }
        }
    }

    float sW = ubits(scal[sWSlot]);
    float sA, sB_;
    if (DUAL) {
        float s1 = fmaxf(ubits(scal[3]), EPSQ) / 255.f;
        sA  = fmaxf(255.f * s1, EPSQ) / 127.f;     // s1b (j codes)
        sB_ = fmaxf(ubits(scal[2]), EPSQ) / 127.f; // sx  (i codes)
    } else {
        sA = fmaxf(ubits(scal[sInSlot]), EPSQ) / 255.f;
        sB_ = 0.f;
    }

    if (MODE == 0) {
        float mm = 0.f;
        #pragma unroll
        for (int f = 0; f < F; f++)
        #pragma unroll
        for (int fn = 0; fn < 4; fn++)
        #pragma unroll
        for (int r = 0; r < 4; r++) {
            int o = oB + oW + f * 16 + (lane >> 4) * 4 + r;
            float av;
            if (DUAL) av = sA * (float)accA[f][fn][r] + sB_ * (float)accB[f][fn][r];
            else      av = sA * (float)(accA[f][fn][r] + (corrI[o] << 7));
            float v = fmaxf(sW * av + bias[o], 0.f);
            mm = fmaxf(mm, v);
        }
        block_max_atomic2(mm, mslot, reinterpret_cast<float*>(lds));
    } else {
        float sOut = fmaxf(ubits(scal[sOutSlot]), EPSQ) / 255.f;
        __syncthreads();
        #pragma unroll
        for (int f = 0; f < F; f++)
        #pragma unroll
        for (int fn = 0; fn < 4; fn++) {
            int orow0 = oW + f * 16 + (lane >> 4) * 4;
            unsigned pk = 0;
            #pragma unroll
            for (int r = 0; r < 4; r++) {
                int o = oB + orow0 + r;
                float av;
                if (DUAL) av = sA * (float)accA[f][fn][r] + sB_ * (float)accB[f][fn][r];
                else      av = sA * (float)(accA[f][fn][r] + (corrI[o] << 7));
                float v = fmaxf(sW * av + bias[o], 0.f);
                int code = (int)fminf(rintf(v / sOut), 255.f) - 128;   // shifted storage
                pk |= ((unsigned)(unsigned char)(i8)code) << (8 * r);
            }
            int pxl = fn * 16 + lane15;
            int ad = (pxl * OB + orow0) ^ ((pxl & 7) << 4);
            *reinterpret_cast<int*>(lds + ad) = (int)pk;
        }
        __syncthreads();
        constexpr int CH = OB / 16;       // 16B chunks per px row
        for (int s = threadIdx.x; s < 64 * CH; s += 256) {
            int px = s / CH, sl = s % CH;
            int ad = (px * OB + sl * 16) ^ ((px & 7) << 4);
            *reinterpret_cast<uint4v*>(outc + (pixbase + px) * O_total + oB + sl * 16) =
                *reinterpret_cast<uint4v*>(lds + ad);
        }
    }
}

// ---------------- 3x3 conv 128->256 i8-MFMA, fp32 NCHW out + max ----------------
// Input codes stored shifted (k-128); OOB cols stage 0x80 (= shifted zero);
// per-o integer correction 128*sum(W) per executed tap-row restores exactness.

__global__ __launch_bounds__(256) void conv3x3_mfma_kernel(
    const i8* __restrict__ xc,    // NHWC shifted codes [B*HW][128]
    const i8* __restrict__ wc,    // packed [16][9][2][64][16]
    const float* __restrict__ bias, float* __restrict__ out,
    const unsigned* __restrict__ scal, const int* __restrict__ corrU,
    unsigned* mslot) {

    __shared__ __align__(16) i8 lds[3 * 66 * 128];
    int lane = threadIdx.x & 63, wv = threadIdx.x >> 6;
    int lane15 = lane & 15;
    int bx = blockIdx.x;
    int b = bx >> 8, h = (bx >> 1) & 127, wseg = bx & 1;
    int oW = wv * 64;

    // stage 3 rows x 66 cols x 128 ch (i8); OOB cols = 0x80 (shifted zero)
    for (int s = threadIdx.x; s < 3 * 66 * 8; s += 256) {
        int row = s / (66 * 8), rem = s % (66 * 8), col = rem >> 3, sl = rem & 7;
        int hh = h + row - 1;
        if (hh < 0 || hh > 127) continue;      // row's taps skipped entirely
        int wgl = wseg * 64 + col - 1;
        uint4v v = {0x80808080u, 0x80808080u, 0x80808080u, 0x80808080u};
        if (wgl >= 0 && wgl <= 127) {
            long pix = (long)b * HW + (long)hh * 128 + wgl;
            v = *reinterpret_cast<const uint4v*>(xc + pix * 128 + sl * 16);
        }
        int addr = ((row * 66 + col) * 128 + sl * 16) ^ ((col & 7) << 4);
        *reinterpret_cast<uint4v*>(lds + addr) = v;
    }
    __syncthreads();

    const int4v z4 = {0, 0, 0, 0};
    int4v acc[4][4];
    #pragma unroll
    for (int i = 0; i < 4; i++)
        #pragma unroll
        for (int j = 0; j < 4; j++) acc[i][j] = z4;

    const i8* wpack = wc + (long)(wv * 4) * 18 * 1024 + lane * 16;  // otile0 = wv*4
    for (int di = 0; di < 3; di++) {
        int hh = h + di - 1;
        if (hh < 0 || hh > 127) continue;      // block-uniform
        for (int dj = 0; dj < 3; dj++) {
            int tap = di * 3 + dj;
            #pragma unroll
            for (int kb = 0; kb < 2; kb++) {
                int4v a[4];
                #pragma unroll
                for (int f = 0; f < 4; f++)
                    a[f] = *reinterpret_cast<const int4v*>(
                        wpack + ((long)(f * 9 + tap) * 2 + kb) * 1024);
                int4v bb[4];
                #pragma unroll
                for (int fn = 0; fn < 4; fn++) {
                    int col = fn * 16 + lane15 + dj;
                    bb[fn] = *reinterpret_cast<const int4v*>(lds +
                        (((di * 66 + col) * 128 + kb * 64 + (lane >> 4) * 16) ^ ((col & 7) << 4)));
                }
                #pragma unroll
                for (int f = 0; f < 4; f++)
                    #pragma unroll
                    for (int fn = 0; fn < 4; fn++)
                        acc[f][fn] = MFMAI8(a[f], bb[fn], acc[f][fn]);
            }
        }
    }

    float s5 = fmaxf(ubits(scal[5]), EPSQ) / 255.f;
    float sc = ubits(scal[10]) * s5;
    float mm = 0.f;
    #pragma unroll
    for (int f = 0; f < 4; f++)
    #pragma unroll
    for (int r = 0; r < 4; r++) {
        int o = oW + f * 16 + (lane >> 4) * 4 + r;
        int csum = corrU[256 + o];
        if (h > 0)   csum += corrU[o];
        if (h < 127) csum += corrU[512 + o];
        #pragma unroll
        for (int fn = 0; fn < 4; fn++) {
            int px = wseg * 64 + fn * 16 + lane15;
            int ai = acc[f][fn][r] + (csum << 7);
            float v = fmaxf(sc * (float)ai + bias[o], 0.f);
            mm = fmaxf(mm, v);
            out[((long)(b * CO + o)) * HW + h * 128 + px] = v;
        }
    }
    block_max_atomic2(mm, mslot, reinterpret_cast<float*>(lds));
}

// ---------------- in-place quant of a relu'd tensor (255 levels) ----------------

__global__ void quant_inplace_kernel(float4* __restrict__ p, long n4,
                                     const unsigned* __restrict__ scal, int idx) {
    float s = fmaxf(__uint_as_float(scal[idx]), EPSQ) / 255.f;
    long i0 = (long)blockIdx.x * blockDim.x + threadIdx.x;
    long str = (long)gridDim.x * blockDim.x;
    for (long i = i0; i < n4; i += str) {
        float4 v = p[i];
        v.x = fminf(rintf(v.x / s), 255.f) * s;
        v.y = fminf(rintf(v.y / s), 255.f) * s;
        v.z = fminf(rintf(v.z / s), 255.f) * s;
        v.w = fminf(rintf(v.w / s), 255.f) * s;
        p[i] = v;
    }
}

// ---------------- launch ----------------

extern "C" void kernel_launch(void* const* d_in, const int* in_sizes, int n_in,
                              void* d_out, int out_size, void* d_ws, size_t ws_size,
                              hipStream_t stream) {
    (void)in_sizes; (void)n_in; (void)out_size; (void)ws_size;
    const float* x     = (const float*)d_in[0];
    const float* dw1_w = (const float*)d_in[1];
    const float* dw1_b = (const float*)d_in[2];
    const float* dw2_w = (const float*)d_in[3];
    const float* dw2_b = (const float*)d_in[4];
    const float* pw1_w = (const float*)d_in[5];
    const float* pw1_b = (const float*)d_in[6];
    const float* pw2_w = (const float*)d_in[7];
    const float* pw2_b = (const float*)d_in[8];
    const float* up_w  = (const float*)d_in[9];
    const float* up_b  = (const float*)d_in[10];
    float* out = (float*)d_out;
    float* ws  = (float*)d_ws;

    // ws layout (float units):
    // [0, NX)          Abuf fp32          (later: p1codes i8, NP1 bytes = NX*4 B exact fit)
    // [NX, 2NX)        Bbuf fp32
    // [2NX, 2NX+NX/4)  jcode i8 NX bytes  (later: p2codes i8 NX bytes)
    // [2NX+NX/4, 2NX+NX/2) icode i8 NX bytes
    // [3NX, ...)       weight area + scal + corr
    float* Abuf = ws;
    float* Bbuf = ws + NX;
    i8*    jcode   = (i8*)(ws + 2 * NX);
    i8*    icode   = jcode + NX;
    i8*    p1codes = (i8*)ws;
    i8*    p2codes = (i8*)(ws + 2 * NX);

    float* wbase  = ws + 3 * NX;
    float* wq_dw1 = wbase;          float* bq_dw1 = wbase + 1152;
    float* wq_dw2 = wbase + 1280;   float* bq_dw2 = wbase + 2432;
    float* bq_pw1 = wbase + 2560;
    float* bq_pw2 = wbase + 3072;
    float* bq_up  = wbase + 3200;
    i8*    wc_pw1 = (i8*)(wbase + 3456);    // 65536 B
    i8*    wc_pw2 = (i8*)(wbase + 19840);   // 65536 B
    i8*    wc_up  = (i8*)(wbase + 36224);   // 294912 B
    unsigned* scal = (unsigned*)(wbase + 109952);
    int*   corrU  = (int*)(wbase + 109984);   // [3][256]
    int*   corrP2 = (int*)(wbase + 110752);   // [128]
    // scal slots: 0 SX | 1 M1 | 2 MR1 | 3 M2 | 4 M3(pw1 relu) | 5 M4(pw2 relu)
    //             6 M5(up relu) | 8 sW_pw1 | 9 sW_pw2 | 10 sW_up | 16..25 weight absmax

    (void)hipMemsetAsync(scal, 0, 32 * sizeof(unsigned), stream);

    QW q0{dw1_w, wq_dw1, nullptr, 1152, 0, 0, 9},
       q1{dw1_b, bq_dw1, nullptr, 128, 0, 0, 1},
       q2{dw2_w, wq_dw2, nullptr, 1152, 0, 0, 9},
       q3{dw2_b, bq_dw2, nullptr, 128, 0, 0, 1},
       q4{pw1_w, nullptr, wc_pw1, 65536, 1, 8, 128},
       q5{pw1_b, bq_pw1, nullptr, 512, 0, 0, 1},
       q6{pw2_w, nullptr, wc_pw2, 65536, 1, 9, 512},
       q7{pw2_b, bq_pw2, nullptr, 128, 0, 0, 1},
       q8{up_w, nullptr, wc_up, 294912, 2, 10, 128},
       q9{up_b, bq_up, nullptr, 256, 0, 0, 1};
    wabsmax_kernel<<<dim3(32, 10), 256, 0, stream>>>(q0, q1, q2, q3, q4, q5, q6, q7, q8, q9, scal);
    wquant_kernel<<<dim3(32, 10), 256, 0, stream>>>(q0, q1, q2, q3, q4, q5, q6, q7, q8, q9, scal);
    corr_kernel<<<dim3(256, 2), 64, 0, stream>>>(pw2_w, up_w, scal, corrP2, corrU);

    absmax_kernel<<<2048, 256, 0, stream>>>(x, NX, scal + 0);

    // residual block 1 (fp32 path)
    dwconv_kernel<<<dim3(Bn * Cc, Hh / 8), 256, 0, stream>>>(x, wq_dw1, bq_dw1, Abuf, scal + 1);
    residual_kernel<<<4096, 256, 0, stream>>>((const float4*)Abuf, (const float4*)x,
                                              (float4*)Bbuf, scal, 1, 0, scal + 2);
    // residual block 2 -> i8 NHWC code planes
    dwconv_kernel<<<dim3(Bn * Cc, Hh / 8), 256, 0, stream>>>(Bbuf, wq_dw2, bq_dw2, Abuf, scal + 3);
    residual2_codes_kernel<<<2048, 256, 0, stream>>>(Abuf, Bbuf, jcode, icode, scal);

    // pw1 (dual-plane exact GEMM): pass1 max -> slot4, pass2 shifted codes -> p1codes
    pwmfma_kernel<128, 256, true, 0><<<dim3(2048, 2), 256, 0, stream>>>(
        jcode, icode, wc_pw1, bq_pw1, nullptr, scal, nullptr, C4, 0, 8, 0, scal + 4);
    pwmfma_kernel<128, 256, true, 1><<<dim3(2048, 2), 256, 0, stream>>>(
        jcode, icode, wc_pw1, bq_pw1, p1codes, scal, nullptr, C4, 0, 8, 4, nullptr);

    // pw2: shifted input (corrP2), pass1 max -> slot5, pass2 shifted codes -> p2codes
    pwmfma_kernel<512, 128, false, 0><<<dim3(2048, 1), 256, 0, stream>>>(
        p1codes, nullptr, wc_pw2, bq_pw2, nullptr, scal, corrP2, Cc, 4, 9, 0, scal + 5);
    pwmfma_kernel<512, 128, false, 1><<<dim3(2048, 1), 256, 0, stream>>>(
        p1codes, nullptr, wc_pw2, bq_pw2, p2codes, scal, corrP2, Cc, 4, 9, 5, nullptr);

    // up 3x3 -> d_out fp32 + max slot6, then final quant in place
    conv3x3_mfma_kernel<<<2048, 256, 0, stream>>>(p2codes, wc_up, bq_up, out, scal, corrU, scal + 6);
    quant_inplace_kernel<<<4096, 256, 0, stream>>>((float4*)out, NOUT / 4, scal, 6);
}

// Round 9
// 523.419 us; speedup vs baseline: 1.6542x; 1.0917x over previous
//
#include <hip/hip_runtime.h>

#define EPSQ 1e-8f

typedef unsigned short u16;
typedef signed char i8;
typedef __attribute__((ext_vector_type(4))) int int4v;
typedef __attribute__((ext_vector_type(4))) unsigned int uint4v;

static constexpr int  Bn = 8, Cc = 128, Hh = 128, Ww = 128, HW = Hh * Ww; // 16384
static constexpr int  C4 = 512, CO = 256;
static constexpr long NX   = (long)Bn * Cc * HW;   // 16,777,216
static constexpr long NOUT = (long)Bn * CO * HW;   // 33,554,432

#define MFMAI8(a,b,c) __builtin_amdgcn_mfma_i32_16x16x64_i8(a,b,c,0,0,0)

__device__ __forceinline__ float ubits(unsigned u) { return __uint_as_float(u); }

__device__ __forceinline__ float4 fma4(float a, float4 b, float4 c) {
    float4 r;
    r.x = fmaf(a, b.x, c.x); r.y = fmaf(a, b.y, c.y);
    r.z = fmaf(a, b.z, c.z); r.w = fmaf(a, b.w, c.w);
    return r;
}

// ---------------- reductions ----------------

__device__ __forceinline__ void block_max_atomic(float v, unsigned* slot) {
    #pragma unroll
    for (int off = 32; off; off >>= 1) v = fmaxf(v, __shfl_down(v, off));
    __shared__ float sm[8];
    int lane = threadIdx.x & 63, wid = threadIdx.x >> 6;
    if (lane == 0) sm[wid] = v;
    __syncthreads();
    if (threadIdx.x == 0) {
        float m = sm[0];
        int nw = (blockDim.x + 63) >> 6;
        for (int i = 1; i < nw; i++) m = fmaxf(m, sm[i]);
        if (m > __uint_as_float(*(volatile unsigned*)slot))
            atomicMax(slot, __float_as_uint(m));
    }
    __syncthreads();
}

// version with caller-provided LDS scratch
__device__ __forceinline__ void block_max_atomic2(float v, unsigned* slot, float* sm) {
    #pragma unroll
    for (int off = 32; off; off >>= 1) v = fmaxf(v, __shfl_down(v, off));
    int lane = threadIdx.x & 63, wid = threadIdx.x >> 6;
    __syncthreads();
    if (lane == 0) sm[wid] = v;
    __syncthreads();
    if (threadIdx.x == 0) {
        float m = sm[0];
        int nw = (blockDim.x + 63) >> 6;
        for (int i = 1; i < nw; i++) m = fmaxf(m, sm[i]);
        if (m > __uint_as_float(*(volatile unsigned*)slot))
            atomicMax(slot, __float_as_uint(m));
    }
}

// ---------------- weight fake-quant ----------------
// mode 0: fp32 dequant to dstF.
// mode 1: i8 codes packed for 16x16x64 MFMA: [otile][kb(64)][lane][16], o=otile*16+(lane&15),
//         k=kb*64+(lane>>4)*16+e.
// mode 2: 3x3 (K=128): [otile][tap][kb][lane][16].
struct QW { const float* src; float* dstF; i8* dstC; int n; int mode; int slot; int kdim; };

__device__ __forceinline__ QW qw_select(const QW& q0, const QW& q1, const QW& q2, const QW& q3,
                                        const QW& q4, const QW& q5, const QW& q6, const QW& q7,
                                        const QW& q8, const QW& q9, int t) {
    switch (t) {
        case 0: return q0; case 1: return q1; case 2: return q2; case 3: return q3;
        case 4: return q4; case 5: return q5; case 6: return q6; case 7: return q7;
        case 8: return q8; default: return q9;
    }
}

__global__ void wabsmax_kernel(QW q0, QW q1, QW q2, QW q3, QW q4,
                               QW q5, QW q6, QW q7, QW q8, QW q9,
                               unsigned* __restrict__ scal) {
    QW q = qw_select(q0, q1, q2, q3, q4, q5, q6, q7, q8, q9, blockIdx.y);
    int i0 = blockIdx.x * blockDim.x + threadIdx.x;
    int str = gridDim.x * blockDim.x;
    float m = 0.f;
    for (int i = i0; i < q.n; i += str) m = fmaxf(m, fabsf(q.src[i]));
    block_max_atomic(m, scal + 16 + blockIdx.y);
}

__global__ void wquant_kernel(QW q0, QW q1, QW q2, QW q3, QW q4,
                              QW q5, QW q6, QW q7, QW q8, QW q9,
                              unsigned* __restrict__ scal) {
    QW q = qw_select(q0, q1, q2, q3, q4, q5, q6, q7, q8, q9, blockIdx.y);
    float s = fmaxf(ubits(scal[16 + blockIdx.y]), EPSQ) / 127.f;
    if (q.mode != 0 && blockIdx.x == 0 && threadIdx.x == 0) scal[q.slot] = __float_as_uint(s);
    int i0 = blockIdx.x * blockDim.x + threadIdx.x;
    int str = gridDim.x * blockDim.x;
    for (int i = i0; i < q.n; i += str) {
        float v = fminf(fmaxf(rintf(q.src[i] / s), -127.f), 127.f);
        int code = (int)v;
        if (q.mode == 0) q.dstF[i] = v * s;
        else if (q.mode == 1) {
            int o = i / q.kdim, k = i % q.kdim;
            int otile = o >> 4, r = o & 15, kb = k >> 6, qq = (k & 63) >> 4, e = k & 15;
            q.dstC[((otile * (q.kdim >> 6) + kb) * 64 + qq * 16 + r) * 16 + e] = (i8)code;
        } else {
            int o = i / 1152, rem = i % 1152, c = rem / 9, t = rem % 9;
            int otile = o >> 4, r = o & 15, kb = c >> 6, qq = (c & 63) >> 4, e = c & 15;
            q.dstC[(((otile * 9 + t) * 2 + kb) * 64 + qq * 16 + r) * 16 + e] = (i8)code;
        }
    }
}

// ---------------- shift-correction sums (atomic-free, 1 wave per output ch) ----------------

__global__ void corr_kernel(const float* __restrict__ pw2_w, const float* __restrict__ up_w,
                            const unsigned* __restrict__ scal,
                            int* __restrict__ corrP2, int* __restrict__ corrU) {
    int lane = threadIdx.x;           // 64 threads
    if (blockIdx.y == 0) {
        int o = blockIdx.x;
        if (o >= 128) return;
        float s = fmaxf(ubits(scal[16 + 6]), EPSQ) / 127.f;
        int sum = 0;
        for (int k = lane; k < 512; k += 64)
            sum += (int)fminf(fmaxf(rintf(pw2_w[o * 512 + k] / s), -127.f), 127.f);
        #pragma unroll
        for (int off = 32; off; off >>= 1) sum += __shfl_down(sum, off);
        if (lane == 0) corrP2[o] = sum;
    } else {
        int o = blockIdx.x;
        float s = fmaxf(ubits(scal[16 + 8]), EPSQ) / 127.f;
        int sum[3] = {0, 0, 0};
        for (int i = lane; i < 1152; i += 64) {
            int t = i % 9;
            int code = (int)fminf(fmaxf(rintf(up_w[o * 1152 + i] / s), -127.f), 127.f);
            sum[t / 3] += code;
        }
        #pragma unroll
        for (int r = 0; r < 3; r++) {
            int v = sum[r];
            #pragma unroll
            for (int off = 32; off; off >>= 1) v += __shfl_down(v, off);
            if (lane == 0) corrU[r * 256 + o] = v;
        }
    }
}

// ---------------- depthwise 3x3 (pad 1), fp32, vectorized float4 ----------------
// Thread: 2 rows x 4 px. Optionally fuses absmax(|in|) via center loads (full coverage).

__global__ __launch_bounds__(256) void dwconv_kernel(
    const float* __restrict__ in, const float* __restrict__ wq,
    const float* __restrict__ bq, float* __restrict__ out,
    unsigned* mslot, unsigned* xslot) {
    int bc = blockIdx.x;              // b*C + c
    int c  = bc & (Cc - 1);
    float w[9];
    #pragma unroll
    for (int k = 0; k < 9; k++) w[k] = wq[c * 9 + k];
    float bias = bq[c];
    const float* src = in + (long)bc * HW;
    float* dst = out + (long)bc * HW;
    int tg = threadIdx.x & 31;        // col group: j0 = tg*4
    int rh = threadIdx.x >> 5;        // 0..7
    int j0 = tg * 4;
    int r0 = blockIdx.y * 16 + rh * 2;

    const float4 z4 = {0.f, 0.f, 0.f, 0.f};
    float4 L[4], C[4], R[4];
    float mx = 0.f;
    #pragma unroll
    for (int t = 0; t < 4; t++) {
        int row = r0 - 1 + t;
        if (row < 0 || row > 127) { L[t] = z4; C[t] = z4; R[t] = z4; continue; }
        const float* p = src + row * Ww + j0;
        float4 cv = *reinterpret_cast<const float4*>(p);
        C[t] = cv;
        L[t] = (j0 > 0)   ? *reinterpret_cast<const float4*>(p - 4) : z4;
        R[t] = (j0 < 124) ? *reinterpret_cast<const float4*>(p + 4) : z4;
        mx = fmaxf(mx, fmaxf(fmaxf(fabsf(cv.x), fabsf(cv.y)),
                             fmaxf(fabsf(cv.z), fabsf(cv.w))));
    }

    float mm = 0.f;
    #pragma unroll
    for (int rr = 0; rr < 2; rr++) {
        float4 acc = {bias, bias, bias, bias};
        #pragma unroll
        for (int t = 0; t < 3; t++) {
            float4 l = L[rr + t], cc = C[rr + t], r = R[rr + t];
            float4 wm1 = {l.w, cc.x, cc.y, cc.z};
            float4 wp1 = {cc.y, cc.z, cc.w, r.x};
            acc = fma4(w[t * 3 + 0], wm1, acc);
            acc = fma4(w[t * 3 + 1], cc,  acc);
            acc = fma4(w[t * 3 + 2], wp1, acc);
        }
        *reinterpret_cast<float4*>(dst + (r0 + rr) * Ww + j0) = acc;
        mm = fmaxf(mm, fmaxf(fmaxf(acc.x, acc.y), fmaxf(acc.z, acc.w)));
    }
    block_max_atomic(fmaxf(mm, 0.f), mslot);
    if (xslot) block_max_atomic(mx, xslot);
}

// ---------------- residual 1: r = fq(quant_relu(t)) + fq(x), fp32 out + max ----------------

__global__ void residual_kernel(const float4* __restrict__ t, const float4* __restrict__ xin,
                                float4* __restrict__ r, const unsigned* __restrict__ scal,
                                int mReluIdx, int mXIdx, unsigned* mOut) {
    float s1  = fmaxf(__uint_as_float(scal[mReluIdx]), EPSQ) / 255.f;
    float mh  = 255.f * s1;
    float s1b = fmaxf(mh, EPSQ) / 127.f;
    float sx  = fmaxf(__uint_as_float(scal[mXIdx]), EPSQ) / 127.f;
    long i0 = (long)blockIdx.x * blockDim.x + threadIdx.x;
    long str = (long)gridDim.x * blockDim.x;
    long n4 = NX >> 2;
    float mm = 0.f;
    for (long i = i0; i < n4; i += str) {
        float4 tv = t[i];
        float4 xv = xin[i];
        float o[4];
        float tc[4] = {tv.x, tv.y, tv.z, tv.w};
        float xc[4] = {xv.x, xv.y, xv.z, xv.w};
        #pragma unroll
        for (int k = 0; k < 4; k++) {
            float h  = fminf(rintf(fmaxf(tc[k], 0.f) / s1), 255.f) * s1;
            float hq = fminf(fmaxf(rintf(h / s1b), -127.f), 127.f) * s1b;
            float xq = fminf(fmaxf(rintf(xc[k] / sx), -127.f), 127.f) * sx;
            o[k] = hq + xq;
            mm = fmaxf(mm, fabsf(o[k]));
        }
        float4 ov = {o[0], o[1], o[2], o[3]};
        r[i] = ov;
    }
    if (mOut) block_max_atomic(mm, mOut);
}

// ---------------- residual 2: emit NHWC i8 code planes (j from dw2-path, i from r1) ----------------

__global__ __launch_bounds__(256) void residual2_codes_kernel(
    const float* __restrict__ t2, const float* __restrict__ r1,
    i8* __restrict__ jc, i8* __restrict__ ic, const unsigned* __restrict__ scal) {
    float s1  = fmaxf(ubits(scal[3]), EPSQ) / 255.f;
    float s1b = fmaxf(255.f * s1, EPSQ) / 127.f;
    float sx  = fmaxf(ubits(scal[2]), EPSQ) / 127.f;
    int b = blockIdx.x >> 8;
    long px0 = (long)(blockIdx.x & 255) * 64;
    __shared__ __align__(16) i8 lj[64 * 128];
    __shared__ __align__(16) i8 li[64 * 128];
    int px = threadIdx.x & 63, cq = threadIdx.x >> 6;
    for (int it = 0; it < 8; it++) {
        int cb = it * 16 + cq * 4;
        unsigned pj = 0, pi = 0;
        #pragma unroll
        for (int e = 0; e < 4; e++) {
            int c = cb + e;
            long g = ((long)b * Cc + c) * HW + px0 + px;
            float t = t2[g], x = r1[g];
            float hq = fminf(rintf(fmaxf(t, 0.f) / s1), 255.f) * s1;
            int j = (int)fminf(fmaxf(rintf(hq / s1b), -127.f), 127.f);
            int i = (int)fminf(fmaxf(rintf(x / sx), -127.f), 127.f);
            pj |= ((unsigned)(unsigned char)(i8)j) << (8 * e);
            pi |= ((unsigned)(unsigned char)(i8)i) << (8 * e);
        }
        int ad = (px * 128 + cb) ^ ((px & 7) << 4);
        *reinterpret_cast<int*>(lj + ad) = (int)pj;
        *reinterpret_cast<int*>(li + ad) = (int)pi;
    }
    __syncthreads();
    for (int s = threadIdx.x; s < 512; s += 256) {
        int px2 = s >> 3, sl = s & 7;
        int ad = (px2 * 128 + sl * 16) ^ ((px2 & 7) << 4);
        long dst = ((long)b * HW + px0 + px2) * 128 + sl * 16;
        *reinterpret_cast<uint4v*>(jc + dst) = *reinterpret_cast<uint4v*>(lj + ad);
        *reinterpret_cast<uint4v*>(ic + dst) = *reinterpret_cast<uint4v*>(li + ad);
    }
}

// ---------------- pointwise i8-MFMA GEMM over integer codes ----------------
// Block: 256 thr = 4 waves. Tile OB outputs x 64 px. K=64 per MFMA.
// MODE 0: relu max only. MODE 1: write quantized i8 codes (shifted -128) NHWC.
template<int K, int OB, bool DUAL, int MODE>
__global__ __launch_bounds__(256) void pwmfma_kernel(
    const i8* __restrict__ bc0, const i8* __restrict__ bc1,
    const i8* __restrict__ wc, const float* __restrict__ bias,
    i8* __restrict__ outc, const unsigned* __restrict__ scal,
    const int* __restrict__ corrI,
    int O_total, int sInSlot, int sWSlot, int sOutSlot, unsigned* mslot) {

    constexpr int F = OB / 64;                    // o-frags (of 16) per wave
    constexpr int KB = K / 64;
    constexpr int LSZ = (DUAL ? 2 : 1) * 64 * K;
    __shared__ __align__(16) i8 lds[LSZ];
    int lane = threadIdx.x & 63, wv = threadIdx.x >> 6;
    int lane15 = lane & 15;
    int b = blockIdx.x >> 8;
    long px0 = (long)(blockIdx.x & 255) * 64;
    long pixbase = (long)b * HW + px0;
    int oB = blockIdx.y * OB;
    int oW = wv * (OB / 4);

    for (int s = threadIdx.x; s < 4 * K; s += 256) {        // 64 px * K/16 chunks
        int px = s / (K / 16), cs = s % (K / 16);
        long gsrc = (pixbase + px) * K + cs * 16;
        int addr = (px * K + cs * 16) ^ ((px & 7) << 4);
        *reinterpret_cast<uint4v*>(lds + addr) = *reinterpret_cast<const uint4v*>(bc0 + gsrc);
        if (DUAL)
            *reinterpret_cast<uint4v*>(lds + 64 * K + addr) =
                *reinterpret_cast<const uint4v*>(bc1 + gsrc);
    }
    __syncthreads();

    const int4v z4 = {0, 0, 0, 0};
    int4v accA[F][4], accB[F][4];
    #pragma unroll
    for (int i = 0; i < F; i++)
        #pragma unroll
        for (int j = 0; j < 4; j++) { accA[i][j] = z4; accB[i][j] = z4; }

    const i8* wpack = wc + ((long)((oB + oW) >> 4) * KB) * 1024 + lane * 16;

    #pragma unroll
    for (int kb = 0; kb < KB; kb++) {
        int4v a[F];
        #pragma unroll
        for (int f = 0; f < F; f++)
            a[f] = *reinterpret_cast<const int4v*>(wpack + ((long)f * KB + kb) * 1024);
        #pragma unroll
        for (int fn = 0; fn < 4; fn++) {
            int col = fn * 16 + lane15;
            int ad = (col * K + kb * 64 + (lane >> 4) * 16) ^ ((col & 7) << 4);
            int4v b0 = *reinterpret_cast<const int4v*>(lds + ad);
            #pragma unroll
            for (int f = 0; f < F; f++) accA[f][fn] = MFMAI8(a[f], b0, accA[f][fn]);
            if (DUAL) {
                int4v b1 = *reinterpret_cast<const int4v*>(lds + 64 * K + ad);
                #pragma unroll
                for (int f = 0; f < F; f++) accB[f][fn] = MFMAI8(a[f], b1, accB[f][fn]);
            }
        }
    }

    float sW = ubits(scal[sWSlot]);
    float sA, sB_;
    if (DUAL) {
        float s1 = fmaxf(ubits(scal[3]), EPSQ) / 255.f;
        sA  = fmaxf(255.f * s1, EPSQ) / 127.f;     // s1b (j codes)
        sB_ = fmaxf(ubits(scal[2]), EPSQ) / 127.f; // sx  (i codes)
    } else {
        sA = fmaxf(ubits(scal[sInSlot]), EPSQ) / 255.f;
        sB_ = 0.f;
    }

    if (MODE == 0) {
        float mm = 0.f;
        #pragma unroll
        for (int f = 0; f < F; f++)
        #pragma unroll
        for (int fn = 0; fn < 4; fn++)
        #pragma unroll
        for (int r = 0; r < 4; r++) {
            int o = oB + oW + f * 16 + (lane >> 4) * 4 + r;
            float av;
            if (DUAL) av = sA * (float)accA[f][fn][r] + sB_ * (float)accB[f][fn][r];
            else      av = sA * (float)(accA[f][fn][r] + (corrI[o] << 7));
            float v = fmaxf(sW * av + bias[o], 0.f);
            mm = fmaxf(mm, v);
        }
        block_max_atomic2(mm, mslot, reinterpret_cast<float*>(lds));
    } else {
        float sOut = fmaxf(ubits(scal[sOutSlot]), EPSQ) / 255.f;
        __syncthreads();
        #pragma unroll
        for (int f = 0; f < F; f++)
        #pragma unroll
        for (int fn = 0; fn < 4; fn++) {
            int orow0 = oW + f * 16 + (lane >> 4) * 4;
            unsigned pk = 0;
            #pragma unroll
            for (int r = 0; r < 4; r++) {
                int o = oB + orow0 + r;
                float av;
                if (DUAL) av = sA * (float)accA[f][fn][r] + sB_ * (float)accB[f][fn][r];
                else      av = sA * (float)(accA[f][fn][r] + (corrI[o] << 7));
                float v = fmaxf(sW * av + bias[o], 0.f);
                int code = (int)fminf(rintf(v / sOut), 255.f) - 128;   // shifted storage
                pk |= ((unsigned)(unsigned char)(i8)code) << (8 * r);
            }
            int pxl = fn * 16 + lane15;
            int ad = (pxl * OB + orow0) ^ ((pxl & 7) << 4);
            *reinterpret_cast<int*>(lds + ad) = (int)pk;
        }
        __syncthreads();
        constexpr int CH = OB / 16;       // 16B chunks per px row
        for (int s = threadIdx.x; s < 64 * CH; s += 256) {
            int px = s / CH, sl = s % CH;
            int ad = (px * OB + sl * 16) ^ ((px & 7) << 4);
            *reinterpret_cast<uint4v*>(outc + (pixbase + px) * O_total + oB + sl * 16) =
                *reinterpret_cast<uint4v*>(lds + ad);
        }
    }
}

// ---------------- 3x3 conv 128->256 i8-MFMA, fp32 NCHW out + max ----------------

__global__ __launch_bounds__(256) void conv3x3_mfma_kernel(
    const i8* __restrict__ xc,    // NHWC shifted codes [B*HW][128]
    const i8* __restrict__ wc,    // packed [16][9][2][64][16]
    const float* __restrict__ bias, float* __restrict__ out,
    const unsigned* __restrict__ scal, const int* __restrict__ corrU,
    unsigned* mslot) {

    __shared__ __align__(16) i8 lds[3 * 66 * 128];
    int lane = threadIdx.x & 63, wv = threadIdx.x >> 6;
    int lane15 = lane & 15;
    int bx = blockIdx.x;
    int b = bx >> 8, h = (bx >> 1) & 127, wseg = bx & 1;
    int oW = wv * 64;

    // stage 3 rows x 66 cols x 128 ch (i8); OOB cols = 0x80 (shifted zero)
    for (int s = threadIdx.x; s < 3 * 66 * 8; s += 256) {
        int row = s / (66 * 8), rem = s % (66 * 8), col = rem >> 3, sl = rem & 7;
        int hh = h + row - 1;
        if (hh < 0 || hh > 127) continue;      // row's taps skipped entirely
        int wgl = wseg * 64 + col - 1;
        uint4v v = {0x80808080u, 0x80808080u, 0x80808080u, 0x80808080u};
        if (wgl >= 0 && wgl <= 127) {
            long pix = (long)b * HW + (long)hh * 128 + wgl;
            v = *reinterpret_cast<const uint4v*>(xc + pix * 128 + sl * 16);
        }
        int addr = ((row * 66 + col) * 128 + sl * 16) ^ ((col & 7) << 4);
        *reinterpret_cast<uint4v*>(lds + addr) = v;
    }
    __syncthreads();

    const int4v z4 = {0, 0, 0, 0};
    int4v acc[4][4];
    #pragma unroll
    for (int i = 0; i < 4; i++)
        #pragma unroll
        for (int j = 0; j < 4; j++) acc[i][j] = z4;

    const i8* wpack = wc + (long)(wv * 4) * 18 * 1024 + lane * 16;  // otile0 = wv*4
    for (int di = 0; di < 3; di++) {
        int hh = h + di - 1;
        if (hh < 0 || hh > 127) continue;      // block-uniform
        for (int dj = 0; dj < 3; dj++) {
            int tap = di * 3 + dj;
            #pragma unroll
            for (int kb = 0; kb < 2; kb++) {
                int4v a[4];
                #pragma unroll
                for (int f = 0; f < 4; f++)
                    a[f] = *reinterpret_cast<const int4v*>(
                        wpack + ((long)(f * 9 + tap) * 2 + kb) * 1024);
                int4v bb[4];
                #pragma unroll
                for (int fn = 0; fn < 4; fn++) {
                    int col = fn * 16 + lane15 + dj;
                    bb[fn] = *reinterpret_cast<const int4v*>(lds +
                        (((di * 66 + col) * 128 + kb * 64 + (lane >> 4) * 16) ^ ((col & 7) << 4)));
                }
                #pragma unroll
                for (int f = 0; f < 4; f++)
                    #pragma unroll
                    for (int fn = 0; fn < 4; fn++)
                        acc[f][fn] = MFMAI8(a[f], bb[fn], acc[f][fn]);
            }
        }
    }

    float s5 = fmaxf(ubits(scal[5]), EPSQ) / 255.f;
    float sc = ubits(scal[10]) * s5;
    float mm = 0.f;
    #pragma unroll
    for (int f = 0; f < 4; f++)
    #pragma unroll
    for (int r = 0; r < 4; r++) {
        int o = oW + f * 16 + (lane >> 4) * 4 + r;
        int csum = corrU[256 + o];
        if (h > 0)   csum += corrU[o];
        if (h < 127) csum += corrU[512 + o];
        #pragma unroll
        for (int fn = 0; fn < 4; fn++) {
            int px = wseg * 64 + fn * 16 + lane15;
            int ai = acc[f][fn][r] + (csum << 7);
            float v = fmaxf(sc * (float)ai + bias[o], 0.f);
            mm = fmaxf(mm, v);
            out[((long)(b * CO + o)) * HW + h * 128 + px] = v;
        }
    }
    block_max_atomic2(mm, mslot, reinterpret_cast<float*>(lds));
}

// ---------------- in-place quant of a relu'd tensor (255 levels) ----------------

__global__ void quant_inplace_kernel(float4* __restrict__ p, long n4,
                                     const unsigned* __restrict__ scal, int idx) {
    float s = fmaxf(__uint_as_float(scal[idx]), EPSQ) / 255.f;
    long i0 = (long)blockIdx.x * blockDim.x + threadIdx.x;
    long str = (long)gridDim.x * blockDim.x;
    for (long i = i0; i < n4; i += str) {
        float4 v = p[i];
        v.x = fminf(rintf(v.x / s), 255.f) * s;
        v.y = fminf(rintf(v.y / s), 255.f) * s;
        v.z = fminf(rintf(v.z / s), 255.f) * s;
        v.w = fminf(rintf(v.w / s), 255.f) * s;
        p[i] = v;
    }
}

// ---------------- launch ----------------

extern "C" void kernel_launch(void* const* d_in, const int* in_sizes, int n_in,
                              void* d_out, int out_size, void* d_ws, size_t ws_size,
                              hipStream_t stream) {
    (void)in_sizes; (void)n_in; (void)out_size; (void)ws_size;
    const float* x     = (const float*)d_in[0];
    const float* dw1_w = (const float*)d_in[1];
    const float* dw1_b = (const float*)d_in[2];
    const float* dw2_w = (const float*)d_in[3];
    const float* dw2_b = (const float*)d_in[4];
    const float* pw1_w = (const float*)d_in[5];
    const float* pw1_b = (const float*)d_in[6];
    const float* pw2_w = (const float*)d_in[7];
    const float* pw2_b = (const float*)d_in[8];
    const float* up_w  = (const float*)d_in[9];
    const float* up_b  = (const float*)d_in[10];
    float* out = (float*)d_out;
    float* ws  = (float*)d_ws;

    // ws layout (float units):
    // [0, NX)          Abuf fp32          (later: p1codes i8)
    // [NX, 2NX)        Bbuf fp32
    // [2NX, 2NX+NX/4)  jcode i8           (later: p2codes i8)
    // [2NX+NX/4, 2NX+NX/2) icode i8
    // [3NX, ...)       weight area + scal + corr
    float* Abuf = ws;
    float* Bbuf = ws + NX;
    i8*    jcode   = (i8*)(ws + 2 * NX);
    i8*    icode   = jcode + NX;
    i8*    p1codes = (i8*)ws;
    i8*    p2codes = (i8*)(ws + 2 * NX);

    float* wbase  = ws + 3 * NX;
    float* wq_dw1 = wbase;          float* bq_dw1 = wbase + 1152;
    float* wq_dw2 = wbase + 1280;   float* bq_dw2 = wbase + 2432;
    float* bq_pw1 = wbase + 2560;
    float* bq_pw2 = wbase + 3072;
    float* bq_up  = wbase + 3200;
    i8*    wc_pw1 = (i8*)(wbase + 3456);    // 65536 B
    i8*    wc_pw2 = (i8*)(wbase + 19840);   // 65536 B
    i8*    wc_up  = (i8*)(wbase + 36224);   // 294912 B
    unsigned* scal = (unsigned*)(wbase + 109952);
    int*   corrU  = (int*)(wbase + 109984);   // [3][256]
    int*   corrP2 = (int*)(wbase + 110752);   // [128]
    // scal slots: 0 SX | 1 M1 | 2 MR1 | 3 M2 | 4 M3(pw1 relu) | 5 M4(pw2 relu)
    //             6 M5(up relu) | 8 sW_pw1 | 9 sW_pw2 | 10 sW_up | 16..25 weight absmax

    (void)hipMemsetAsync(scal, 0, 32 * sizeof(unsigned), stream);

    QW q0{dw1_w, wq_dw1, nullptr, 1152, 0, 0, 9},
       q1{dw1_b, bq_dw1, nullptr, 128, 0, 0, 1},
       q2{dw2_w, wq_dw2, nullptr, 1152, 0, 0, 9},
       q3{dw2_b, bq_dw2, nullptr, 128, 0, 0, 1},
       q4{pw1_w, nullptr, wc_pw1, 65536, 1, 8, 128},
       q5{pw1_b, bq_pw1, nullptr, 512, 0, 0, 1},
       q6{pw2_w, nullptr, wc_pw2, 65536, 1, 9, 512},
       q7{pw2_b, bq_pw2, nullptr, 128, 0, 0, 1},
       q8{up_w, nullptr, wc_up, 294912, 2, 10, 128},
       q9{up_b, bq_up, nullptr, 256, 0, 0, 1};
    wabsmax_kernel<<<dim3(32, 10), 256, 0, stream>>>(q0, q1, q2, q3, q4, q5, q6, q7, q8, q9, scal);
    wquant_kernel<<<dim3(32, 10), 256, 0, stream>>>(q0, q1, q2, q3, q4, q5, q6, q7, q8, q9, scal);
    corr_kernel<<<dim3(256, 2), 64, 0, stream>>>(pw2_w, up_w, scal, corrP2, corrU);

    // residual block 1 (dwconv1 also computes absmax(x) -> slot 0)
    dwconv_kernel<<<dim3(Bn * Cc, Hh / 16), 256, 0, stream>>>(x, wq_dw1, bq_dw1, Abuf,
                                                              scal + 1, scal + 0);
    residual_kernel<<<4096, 256, 0, stream>>>((const float4*)Abuf, (const float4*)x,
                                              (float4*)Bbuf, scal, 1, 0, scal + 2);
    // residual block 2 -> i8 NHWC code planes
    dwconv_kernel<<<dim3(Bn * Cc, Hh / 16), 256, 0, stream>>>(Bbuf, wq_dw2, bq_dw2, Abuf,
                                                              scal + 3, nullptr);
    residual2_codes_kernel<<<2048, 256, 0, stream>>>(Abuf, Bbuf, jcode, icode, scal);

    // pw1 (dual-plane exact GEMM): pass1 max -> slot4, pass2 shifted codes -> p1codes
    pwmfma_kernel<128, 256, true, 0><<<dim3(2048, 2), 256, 0, stream>>>(
        jcode, icode, wc_pw1, bq_pw1, nullptr, scal, nullptr, C4, 0, 8, 0, scal + 4);
    pwmfma_kernel<128, 256, true, 1><<<dim3(2048, 2), 256, 0, stream>>>(
        jcode, icode, wc_pw1, bq_pw1, p1codes, scal, nullptr, C4, 0, 8, 4, nullptr);

    // pw2: shifted input (corrP2), pass1 max -> slot5, pass2 shifted codes -> p2codes
    pwmfma_kernel<512, 128, false, 0><<<dim3(2048, 1), 256, 0, stream>>>(
        p1codes, nullptr, wc_pw2, bq_pw2, nullptr, scal, corrP2, Cc, 4, 9, 0, scal + 5);
    pwmfma_kernel<512, 128, false, 1><<<dim3(2048, 1), 256, 0, stream>>>(
        p1codes, nullptr, wc_pw2, bq_pw2, p2codes, scal, corrP2, Cc, 4, 9, 5, nullptr);

    // up 3x3 -> d_out fp32 + max slot6, then final quant in place
    conv3x3_mfma_kernel<<<2048, 256, 0, stream>>>(p2codes, wc_up, bq_up, out, scal, corrU, scal + 6);
    quant_inplace_kernel<<<4096, 256, 0, stream>>>((float4*)out, NOUT / 4, scal, 6);
}

// Round 10
// 494.319 us; speedup vs baseline: 1.7515x; 1.0589x over previous
//
#include <hip/hip_runtime.h>

#define EPSQ 1e-8f

typedef unsigned short u16;
typedef signed char i8;
typedef __attribute__((ext_vector_type(4))) int int4v;
typedef __attribute__((ext_vector_type(4))) unsigned int uint4v;

static constexpr int  Bn = 8, Cc = 128, Hh = 128, Ww = 128, HW = Hh * Ww; // 16384
static constexpr int  C4 = 512, CO = 256;
static constexpr long NX   = (long)Bn * Cc * HW;   // 16,777,216
static constexpr long NOUT = (long)Bn * CO * HW;   // 33,554,432

#define MFMAI8(a,b,c) __builtin_amdgcn_mfma_i32_16x16x64_i8(a,b,c,0,0,0)

__device__ __forceinline__ float ubits(unsigned u) { return __uint_as_float(u); }

__device__ __forceinline__ float4 fma4(float a, float4 b, float4 c) {
    float4 r;
    r.x = fmaf(a, b.x, c.x); r.y = fmaf(a, b.y, c.y);
    r.z = fmaf(a, b.z, c.z); r.w = fmaf(a, b.w, c.w);
    return r;
}

// ---------------- reductions ----------------

__device__ __forceinline__ void block_max_atomic(float v, unsigned* slot) {
    #pragma unroll
    for (int off = 32; off; off >>= 1) v = fmaxf(v, __shfl_down(v, off));
    __shared__ float sm[8];
    int lane = threadIdx.x & 63, wid = threadIdx.x >> 6;
    if (lane == 0) sm[wid] = v;
    __syncthreads();
    if (threadIdx.x == 0) {
        float m = sm[0];
        int nw = (blockDim.x + 63) >> 6;
        for (int i = 1; i < nw; i++) m = fmaxf(m, sm[i]);
        if (m > __uint_as_float(*(volatile unsigned*)slot))
            atomicMax(slot, __float_as_uint(m));
    }
    __syncthreads();
}

// version with caller-provided LDS scratch
__device__ __forceinline__ void block_max_atomic2(float v, unsigned* slot, float* sm) {
    #pragma unroll
    for (int off = 32; off; off >>= 1) v = fmaxf(v, __shfl_down(v, off));
    int lane = threadIdx.x & 63, wid = threadIdx.x >> 6;
    __syncthreads();
    if (lane == 0) sm[wid] = v;
    __syncthreads();
    if (threadIdx.x == 0) {
        float m = sm[0];
        int nw = (blockDim.x + 63) >> 6;
        for (int i = 1; i < nw; i++) m = fmaxf(m, sm[i]);
        if (m > __uint_as_float(*(volatile unsigned*)slot))
            atomicMax(slot, __float_as_uint(m));
    }
}

// ---------------- weight fake-quant ----------------
// mode 0: fp32 dequant to dstF.
// mode 1: i8 codes packed for 16x16x64 MFMA: [otile][kb(64)][lane][16], o=otile*16+(lane&15),
//         k=kb*64+(lane>>4)*16+e.
// mode 2: 3x3 (K=128): [otile][tap][kb][lane][16].
struct QW { const float* src; float* dstF; i8* dstC; int n; int mode; int slot; int kdim; };

__device__ __forceinline__ QW qw_select(const QW& q0, const QW& q1, const QW& q2, const QW& q3,
                                        const QW& q4, const QW& q5, const QW& q6, const QW& q7,
                                        const QW& q8, const QW& q9, int t) {
    switch (t) {
        case 0: return q0; case 1: return q1; case 2: return q2; case 3: return q3;
        case 4: return q4; case 5: return q5; case 6: return q6; case 7: return q7;
        case 8: return q8; default: return q9;
    }
}

__global__ void wabsmax_kernel(QW q0, QW q1, QW q2, QW q3, QW q4,
                               QW q5, QW q6, QW q7, QW q8, QW q9,
                               unsigned* __restrict__ scal) {
    QW q = qw_select(q0, q1, q2, q3, q4, q5, q6, q7, q8, q9, blockIdx.y);
    int i0 = blockIdx.x * blockDim.x + threadIdx.x;
    int str = gridDim.x * blockDim.x;
    float m = 0.f;
    for (int i = i0; i < q.n; i += str) m = fmaxf(m, fabsf(q.src[i]));
    block_max_atomic(m, scal + 16 + blockIdx.y);
}

__global__ void wquant_kernel(QW q0, QW q1, QW q2, QW q3, QW q4,
                              QW q5, QW q6, QW q7, QW q8, QW q9,
                              unsigned* __restrict__ scal) {
    QW q = qw_select(q0, q1, q2, q3, q4, q5, q6, q7, q8, q9, blockIdx.y);
    float s = fmaxf(ubits(scal[16 + blockIdx.y]), EPSQ) / 127.f;
    if (q.mode != 0 && blockIdx.x == 0 && threadIdx.x == 0) scal[q.slot] = __float_as_uint(s);
    int i0 = blockIdx.x * blockDim.x + threadIdx.x;
    int str = gridDim.x * blockDim.x;
    for (int i = i0; i < q.n; i += str) {
        float v = fminf(fmaxf(rintf(q.src[i] / s), -127.f), 127.f);
        int code = (int)v;
        if (q.mode == 0) q.dstF[i] = v * s;
        else if (q.mode == 1) {
            int o = i / q.kdim, k = i % q.kdim;
            int otile = o >> 4, r = o & 15, kb = k >> 6, qq = (k & 63) >> 4, e = k & 15;
            q.dstC[((otile * (q.kdim >> 6) + kb) * 64 + qq * 16 + r) * 16 + e] = (i8)code;
        } else {
            int o = i / 1152, rem = i % 1152, c = rem / 9, t = rem % 9;
            int otile = o >> 4, r = o & 15, kb = c >> 6, qq = (c & 63) >> 4, e = c & 15;
            q.dstC[(((otile * 9 + t) * 2 + kb) * 64 + qq * 16 + r) * 16 + e] = (i8)code;
        }
    }
}

// ---------------- shift-correction sums (atomic-free, 1 wave per output ch) ----------------

__global__ void corr_kernel(const float* __restrict__ pw2_w, const float* __restrict__ up_w,
                            const unsigned* __restrict__ scal,
                            int* __restrict__ corrP2, int* __restrict__ corrU) {
    int lane = threadIdx.x;           // 64 threads
    if (blockIdx.y == 0) {
        int o = blockIdx.x;
        if (o >= 128) return;
        float s = fmaxf(ubits(scal[16 + 6]), EPSQ) / 127.f;
        int sum = 0;
        for (int k = lane; k < 512; k += 64)
            sum += (int)fminf(fmaxf(rintf(pw2_w[o * 512 + k] / s), -127.f), 127.f);
        #pragma unroll
        for (int off = 32; off; off >>= 1) sum += __shfl_down(sum, off);
        if (lane == 0) corrP2[o] = sum;
    } else {
        int o = blockIdx.x;
        float s = fmaxf(ubits(scal[16 + 8]), EPSQ) / 127.f;
        int sum[3] = {0, 0, 0};
        for (int i = lane; i < 1152; i += 64) {
            int t = i % 9;
            int code = (int)fminf(fmaxf(rintf(up_w[o * 1152 + i] / s), -127.f), 127.f);
            sum[t / 3] += code;
        }
        #pragma unroll
        for (int r = 0; r < 3; r++) {
            int v = sum[r];
            #pragma unroll
            for (int off = 32; off; off >>= 1) v += __shfl_down(v, off);
            if (lane == 0) corrU[r * 256 + o] = v;
        }
    }
}

// ---------------- depthwise 3x3 (pad 1), fp32, vectorized float4, grid-stride ----------------
// Thread: 2 rows x 4 px per tile; block processes several tiles, ONE atomic pair at end.

__global__ __launch_bounds__(256) void dwconv_kernel(
    const float* __restrict__ in, const float* __restrict__ wq,
    const float* __restrict__ bq, float* __restrict__ out,
    unsigned* mslot, unsigned* xslot) {
    int tg = threadIdx.x & 31;        // col group: j0 = tg*4
    int rh = threadIdx.x >> 5;        // 0..7
    int j0 = tg * 4;
    const float4 z4 = {0.f, 0.f, 0.f, 0.f};
    float mm = 0.f, mx = 0.f;

    for (int tile = blockIdx.x; tile < Bn * Cc * 8; tile += gridDim.x) {
        int bc = tile >> 3, yt = tile & 7;
        int c  = bc & (Cc - 1);
        float w[9];
        #pragma unroll
        for (int k = 0; k < 9; k++) w[k] = wq[c * 9 + k];
        float bias = bq[c];
        const float* src = in + (long)bc * HW;
        float* dst = out + (long)bc * HW;
        int r0 = yt * 16 + rh * 2;

        float4 L[4], C[4], R[4];
        #pragma unroll
        for (int t = 0; t < 4; t++) {
            int row = r0 - 1 + t;
            if (row < 0 || row > 127) { L[t] = z4; C[t] = z4; R[t] = z4; continue; }
            const float* p = src + row * Ww + j0;
            float4 cv = *reinterpret_cast<const float4*>(p);
            C[t] = cv;
            L[t] = (j0 > 0)   ? *reinterpret_cast<const float4*>(p - 4) : z4;
            R[t] = (j0 < 124) ? *reinterpret_cast<const float4*>(p + 4) : z4;
            mx = fmaxf(mx, fmaxf(fmaxf(fabsf(cv.x), fabsf(cv.y)),
                                 fmaxf(fabsf(cv.z), fabsf(cv.w))));
        }

        #pragma unroll
        for (int rr = 0; rr < 2; rr++) {
            float4 acc = {bias, bias, bias, bias};
            #pragma unroll
            for (int t = 0; t < 3; t++) {
                float4 l = L[rr + t], cc = C[rr + t], r = R[rr + t];
                float4 wm1 = {l.w, cc.x, cc.y, cc.z};
                float4 wp1 = {cc.y, cc.z, cc.w, r.x};
                acc = fma4(w[t * 3 + 0], wm1, acc);
                acc = fma4(w[t * 3 + 1], cc,  acc);
                acc = fma4(w[t * 3 + 2], wp1, acc);
            }
            *reinterpret_cast<float4*>(dst + (r0 + rr) * Ww + j0) = acc;
            mm = fmaxf(mm, fmaxf(fmaxf(acc.x, acc.y), fmaxf(acc.z, acc.w)));
        }
    }
    block_max_atomic(fmaxf(mm, 0.f), mslot);
    if (xslot) block_max_atomic(mx, xslot);
}

// ---------------- residual 1: r = fq(quant_relu(t)) + fq(x), fp32 out + max ----------------

__global__ void residual_kernel(const float4* __restrict__ t, const float4* __restrict__ xin,
                                float4* __restrict__ r, const unsigned* __restrict__ scal,
                                int mReluIdx, int mXIdx, unsigned* mOut) {
    float s1  = fmaxf(__uint_as_float(scal[mReluIdx]), EPSQ) / 255.f;
    float mh  = 255.f * s1;
    float s1b = fmaxf(mh, EPSQ) / 127.f;
    float sx  = fmaxf(__uint_as_float(scal[mXIdx]), EPSQ) / 127.f;
    long i0 = (long)blockIdx.x * blockDim.x + threadIdx.x;
    long str = (long)gridDim.x * blockDim.x;
    long n4 = NX >> 2;
    float mm = 0.f;
    for (long i = i0; i < n4; i += str) {
        float4 tv = t[i];
        float4 xv = xin[i];
        float o[4];
        float tc[4] = {tv.x, tv.y, tv.z, tv.w};
        float xc[4] = {xv.x, xv.y, xv.z, xv.w};
        #pragma unroll
        for (int k = 0; k < 4; k++) {
            float h  = fminf(rintf(fmaxf(tc[k], 0.f) / s1), 255.f) * s1;
            float hq = fminf(fmaxf(rintf(h / s1b), -127.f), 127.f) * s1b;
            float xq = fminf(fmaxf(rintf(xc[k] / sx), -127.f), 127.f) * sx;
            o[k] = hq + xq;
            mm = fmaxf(mm, fabsf(o[k]));
        }
        float4 ov = {o[0], o[1], o[2], o[3]};
        r[i] = ov;
    }
    if (mOut) block_max_atomic(mm, mOut);
}

// ---------------- residual 2: emit NHWC i8 code planes (j from dw2-path, i from r1) ----------------

__global__ __launch_bounds__(256) void residual2_codes_kernel(
    const float* __restrict__ t2, const float* __restrict__ r1,
    i8* __restrict__ jc, i8* __restrict__ ic, const unsigned* __restrict__ scal) {
    float s1  = fmaxf(ubits(scal[3]), EPSQ) / 255.f;
    float s1b = fmaxf(255.f * s1, EPSQ) / 127.f;
    float sx  = fmaxf(ubits(scal[2]), EPSQ) / 127.f;
    int b = blockIdx.x >> 8;
    long px0 = (long)(blockIdx.x & 255) * 64;
    __shared__ __align__(16) i8 lj[64 * 128];
    __shared__ __align__(16) i8 li[64 * 128];
    int px = threadIdx.x & 63, cq = threadIdx.x >> 6;
    for (int it = 0; it < 8; it++) {
        int cb = it * 16 + cq * 4;
        unsigned pj = 0, pi = 0;
        #pragma unroll
        for (int e = 0; e < 4; e++) {
            int c = cb + e;
            long g = ((long)b * Cc + c) * HW + px0 + px;
            float t = t2[g], x = r1[g];
            float hq = fminf(rintf(fmaxf(t, 0.f) / s1), 255.f) * s1;
            int j = (int)fminf(fmaxf(rintf(hq / s1b), -127.f), 127.f);
            int i = (int)fminf(fmaxf(rintf(x / sx), -127.f), 127.f);
            pj |= ((unsigned)(unsigned char)(i8)j) << (8 * e);
            pi |= ((unsigned)(unsigned char)(i8)i) << (8 * e);
        }
        int ad = (px * 128 + cb) ^ ((px & 7) << 4);
        *reinterpret_cast<int*>(lj + ad) = (int)pj;
        *reinterpret_cast<int*>(li + ad) = (int)pi;
    }
    __syncthreads();
    for (int s = threadIdx.x; s < 512; s += 256) {
        int px2 = s >> 3, sl = s & 7;
        int ad = (px2 * 128 + sl * 16) ^ ((px2 & 7) << 4);
        long dst = ((long)b * HW + px0 + px2) * 128 + sl * 16;
        *reinterpret_cast<uint4v*>(jc + dst) = *reinterpret_cast<uint4v*>(lj + ad);
        *reinterpret_cast<uint4v*>(ic + dst) = *reinterpret_cast<uint4v*>(li + ad);
    }
}

// ---------------- pointwise i8-MFMA GEMM over integer codes ----------------
// Block: 256 thr = 4 waves. Tile OB outputs x 64 px. K=64 per MFMA.
// MODE 0: relu max only. MODE 1: write quantized i8 codes (shifted -128) NHWC.
template<int K, int OB, bool DUAL, int MODE>
__global__ __launch_bounds__(256) void pwmfma_kernel(
    const i8* __restrict__ bc0, const i8* __restrict__ bc1,
    const i8* __restrict__ wc, const float* __restrict__ bias,
    i8* __restrict__ outc, const unsigned* __restrict__ scal,
    const int* __restrict__ corrI,
    int O_total, int sInSlot, int sWSlot, int sOutSlot, unsigned* mslot) {

    constexpr int F = OB / 64;                    // o-frags (of 16) per wave
    constexpr int KB = K / 64;
    constexpr int LSZ = (DUAL ? 2 : 1) * 64 * K;
    __shared__ __align__(16) i8 lds[LSZ];
    int lane = threadIdx.x & 63, wv = threadIdx.x >> 6;
    int lane15 = lane & 15;
    int b = blockIdx.x >> 8;
    long px0 = (long)(blockIdx.x & 255) * 64;
    long pixbase = (long)b * HW + px0;
    int oB = blockIdx.y * OB;
    int oW = wv * (OB / 4);

    for (int s = threadIdx.x; s < 4 * K; s += 256) {        // 64 px * K/16 chunks
        int px = s / (K / 16), cs = s % (K / 16);
        long gsrc = (pixbase + px) * K + cs * 16;
        int addr = (px * K + cs * 16) ^ ((px & 7) << 4);
        *reinterpret_cast<uint4v*>(lds + addr) = *reinterpret_cast<const uint4v*>(bc0 + gsrc);
        if (DUAL)
            *reinterpret_cast<uint4v*>(lds + 64 * K + addr) =
                *reinterpret_cast<const uint4v*>(bc1 + gsrc);
    }
    __syncthreads();

    const int4v z4 = {0, 0, 0, 0};
    int4v accA[F][4], accB[F][4];
    #pragma unroll
    for (int i = 0; i < F; i++)
        #pragma unroll
        for (int j = 0; j < 4; j++) { accA[i][j] = z4; accB[i][j] = z4; }

    const i8* wpack = wc + ((long)((oB + oW) >> 4) * KB) * 1024 + lane * 16;

    #pragma unroll
    for (int kb = 0; kb < KB; kb++) {
        int4v a[F];
        #pragma unroll
        for (int f = 0; f < F; f++)
            a[f] = *reinterpret_cast<const int4v*>(wpack + ((long)f * KB + kb) * 1024);
        #pragma unroll
        for (int fn = 0; fn < 4; fn++) {
            int col = fn * 16 + lane15;
            int ad = (col * K + kb * 64 + (lane >> 4) * 16) ^ ((col & 7) << 4);
            int4v b0 = *reinterpret_cast<const int4v*>(lds + ad);
            #pragma unroll
            for (int f = 0; f < F; f++) accA[f][fn] = MFMAI8(a[f], b0, accA[f][fn]);
            if (DUAL) {
                int4v b1 = *reinterpret_cast<const int4v*>(lds + 64 * K + ad);
                #pragma unroll
                for (int f = 0; f < F; f++) accB[f][fn] = MFMAI8(a[f], b1, accB[f][fn]);
            }
        }
    }

    float sW = ubits(scal[sWSlot]);
    float sA, sB_;
    if (DUAL) {
        float s1 = fmaxf(ubits(scal[3]), EPSQ) / 255.f;
        sA  = fmaxf(255.f * s1, EPSQ) / 127.f;     // s1b (j codes)
        sB_ = fmaxf(ubits(scal[2]), EPSQ) / 127.f; // sx  (i codes)
    } else {
        sA = fmaxf(ubits(scal[sInSlot]), EPSQ) / 255.f;
        sB_ = 0.f;
    }

    if (MODE == 0) {
        float mm = 0.f;
        #pragma unroll
        for (int f = 0; f < F; f++)
        #pragma unroll
        for (int fn = 0; fn < 4; fn++)
        #pragma unroll
        for (int r = 0; r < 4; r++) {
            int o = oB + oW + f * 16 + (lane >> 4) * 4 + r;
            float av;
            if (DUAL) av = sA * (float)accA[f][fn][r] + sB_ * (float)accB[f][fn][r];
            else      av = sA * (float)(accA[f][fn][r] + (corrI[o] << 7));
            float v = fmaxf(sW * av + bias[o], 0.f);
            mm = fmaxf(mm, v);
        }
        block_max_atomic2(mm, mslot, reinterpret_cast<float*>(lds));
    } else {
        float sOut = fmaxf(ubits(scal[sOutSlot]), EPSQ) / 255.f;
        __syncthreads();
        #pragma unroll
        for (int f = 0; f < F; f++)
        #pragma unroll
        for (int fn = 0; fn < 4; fn++) {
            int orow0 = oW + f * 16 + (lane >> 4) * 4;
            unsigned pk = 0;
            #pragma unroll
            for (int r = 0; r < 4; r++) {
                int o = oB + orow0 + r;
                float av;
                if (DUAL) av = sA * (float)accA[f][fn][r] + sB_ * (float)accB[f][fn][r];
                else      av = sA * (float)(accA[f][fn][r] + (corrI[o] << 7));
                float v = fmaxf(sW * av + bias[o], 0.f);
                int code = (int)fminf(rintf(v / sOut), 255.f) - 128;   // shifted storage
                pk |= ((unsigned)(unsigned char)(i8)code) << (8 * r);
            }
            int pxl = fn * 16 + lane15;
            int ad = (pxl * OB + orow0) ^ ((pxl & 7) << 4);
            *reinterpret_cast<int*>(lds + ad) = (int)pk;
        }
        __syncthreads();
        constexpr int CH = OB / 16;       // 16B chunks per px row
        for (int s = threadIdx.x; s < 64 * CH; s += 256) {
            int px = s / CH, sl = s % CH;
            int ad = (px * OB + sl * 16) ^ ((px & 7) << 4);
            *reinterpret_cast<uint4v*>(outc + (pixbase + px) * O_total + oB + sl * 16) =
                *reinterpret_cast<uint4v*>(lds + ad);
        }
    }
}

// ---------------- 3x3 conv 128->256 i8-MFMA, fp32 NCHW out + max ----------------

__global__ __launch_bounds__(256) void conv3x3_mfma_kernel(
    const i8* __restrict__ xc,    // NHWC shifted codes [B*HW][128]
    const i8* __restrict__ wc,    // packed [16][9][2][64][16]
    const float* __restrict__ bias, float* __restrict__ out,
    const unsigned* __restrict__ scal, const int* __restrict__ corrU,
    unsigned* mslot) {

    __shared__ __align__(16) i8 lds[3 * 66 * 128];
    int lane = threadIdx.x & 63, wv = threadIdx.x >> 6;
    int lane15 = lane & 15;
    int bx = blockIdx.x;
    int b = bx >> 8, h = (bx >> 1) & 127, wseg = bx & 1;
    int oW = wv * 64;

    // stage 3 rows x 66 cols x 128 ch (i8); OOB cols = 0x80 (shifted zero)
    for (int s = threadIdx.x; s < 3 * 66 * 8; s += 256) {
        int row = s / (66 * 8), rem = s % (66 * 8), col = rem >> 3, sl = rem & 7;
        int hh = h + row - 1;
        if (hh < 0 || hh > 127) continue;      // row's taps skipped entirely
        int wgl = wseg * 64 + col - 1;
        uint4v v = {0x80808080u, 0x80808080u, 0x80808080u, 0x80808080u};
        if (wgl >= 0 && wgl <= 127) {
            long pix = (long)b * HW + (long)hh * 128 + wgl;
            v = *reinterpret_cast<const uint4v*>(xc + pix * 128 + sl * 16);
        }
        int addr = ((row * 66 + col) * 128 + sl * 16) ^ ((col & 7) << 4);
        *reinterpret_cast<uint4v*>(lds + addr) = v;
    }
    __syncthreads();

    const int4v z4 = {0, 0, 0, 0};
    int4v acc[4][4];
    #pragma unroll
    for (int i = 0; i < 4; i++)
        #pragma unroll
        for (int j = 0; j < 4; j++) acc[i][j] = z4;

    const i8* wpack = wc + (long)(wv * 4) * 18 * 1024 + lane * 16;  // otile0 = wv*4
    for (int di = 0; di < 3; di++) {
        int hh = h + di - 1;
        if (hh < 0 || hh > 127) continue;      // block-uniform
        for (int dj = 0; dj < 3; dj++) {
            int tap = di * 3 + dj;
            #pragma unroll
            for (int kb = 0; kb < 2; kb++) {
                int4v a[4];
                #pragma unroll
                for (int f = 0; f < 4; f++)
                    a[f] = *reinterpret_cast<const int4v*>(
                        wpack + ((long)(f * 9 + tap) * 2 + kb) * 1024);
                int4v bb[4];
                #pragma unroll
                for (int fn = 0; fn < 4; fn++) {
                    int col = fn * 16 + lane15 + dj;
                    bb[fn] = *reinterpret_cast<const int4v*>(lds +
                        (((di * 66 + col) * 128 + kb * 64 + (lane >> 4) * 16) ^ ((col & 7) << 4)));
                }
                #pragma unroll
                for (int f = 0; f < 4; f++)
                    #pragma unroll
                    for (int fn = 0; fn < 4; fn++)
                        acc[f][fn] = MFMAI8(a[f], bb[fn], acc[f][fn]);
            }
        }
    }

    float s5 = fmaxf(ubits(scal[5]), EPSQ) / 255.f;
    float sc = ubits(scal[10]) * s5;
    float mm = 0.f;
    #pragma unroll
    for (int f = 0; f < 4; f++)
    #pragma unroll
    for (int r = 0; r < 4; r++) {
        int o = oW + f * 16 + (lane >> 4) * 4 + r;
        int csum = corrU[256 + o];
        if (h > 0)   csum += corrU[o];
        if (h < 127) csum += corrU[512 + o];
        #pragma unroll
        for (int fn = 0; fn < 4; fn++) {
            int px = wseg * 64 + fn * 16 + lane15;
            int ai = acc[f][fn][r] + (csum << 7);
            float v = fmaxf(sc * (float)ai + bias[o], 0.f);
            mm = fmaxf(mm, v);
            out[((long)(b * CO + o)) * HW + h * 128 + px] = v;
        }
    }
    block_max_atomic2(mm, mslot, reinterpret_cast<float*>(lds));
}

// ---------------- in-place quant of a relu'd tensor (255 levels) ----------------

__global__ void quant_inplace_kernel(float4* __restrict__ p, long n4,
                                     const unsigned* __restrict__ scal, int idx) {
    float s = fmaxf(__uint_as_float(scal[idx]), EPSQ) / 255.f;
    long i0 = (long)blockIdx.x * blockDim.x + threadIdx.x;
    long str = (long)gridDim.x * blockDim.x;
    for (long i = i0; i < n4; i += str) {
        float4 v = p[i];
        v.x = fminf(rintf(v.x / s), 255.f) * s;
        v.y = fminf(rintf(v.y / s), 255.f) * s;
        v.z = fminf(rintf(v.z / s), 255.f) * s;
        v.w = fminf(rintf(v.w / s), 255.f) * s;
        p[i] = v;
    }
}

// ---------------- launch ----------------

extern "C" void kernel_launch(void* const* d_in, const int* in_sizes, int n_in,
                              void* d_out, int out_size, void* d_ws, size_t ws_size,
                              hipStream_t stream) {
    (void)in_sizes; (void)n_in; (void)out_size; (void)ws_size;
    const float* x     = (const float*)d_in[0];
    const float* dw1_w = (const float*)d_in[1];
    const float* dw1_b = (const float*)d_in[2];
    const float* dw2_w = (const float*)d_in[3];
    const float* dw2_b = (const float*)d_in[4];
    const float* pw1_w = (const float*)d_in[5];
    const float* pw1_b = (const float*)d_in[6];
    const float* pw2_w = (const float*)d_in[7];
    const float* pw2_b = (const float*)d_in[8];
    const float* up_w  = (const float*)d_in[9];
    const float* up_b  = (const float*)d_in[10];
    float* out = (float*)d_out;
    float* ws  = (float*)d_ws;

    // ws layout (float units):
    // [0, NX)          Abuf fp32          (later: p1codes i8)
    // [NX, 2NX)        Bbuf fp32
    // [2NX, 2NX+NX/4)  jcode i8           (later: p2codes i8)
    // [2NX+NX/4, 2NX+NX/2) icode i8
    // [3NX, ...)       weight area + scal + corr
    float* Abuf = ws;
    float* Bbuf = ws + NX;
    i8*    jcode   = (i8*)(ws + 2 * NX);
    i8*    icode   = jcode + NX;
    i8*    p1codes = (i8*)ws;
    i8*    p2codes = (i8*)(ws + 2 * NX);

    float* wbase  = ws + 3 * NX;
    float* wq_dw1 = wbase;          float* bq_dw1 = wbase + 1152;
    float* wq_dw2 = wbase + 1280;   float* bq_dw2 = wbase + 2432;
    float* bq_pw1 = wbase + 2560;
    float* bq_pw2 = wbase + 3072;
    float* bq_up  = wbase + 3200;
    i8*    wc_pw1 = (i8*)(wbase + 3456);    // 65536 B
    i8*    wc_pw2 = (i8*)(wbase + 19840);   // 65536 B
    i8*    wc_up  = (i8*)(wbase + 36224);   // 294912 B
    unsigned* scal = (unsigned*)(wbase + 109952);
    int*   corrU  = (int*)(wbase + 109984);   // [3][256]
    int*   corrP2 = (int*)(wbase + 110752);   // [128]
    // scal slots: 0 SX | 1 M1 | 2 MR1 | 3 M2 | 4 M3(pw1 relu) | 5 M4(pw2 relu)
    //             6 M5(up relu) | 8 sW_pw1 | 9 sW_pw2 | 10 sW_up | 16..25 weight absmax

    (void)hipMemsetAsync(scal, 0, 32 * sizeof(unsigned), stream);

    QW q0{dw1_w, wq_dw1, nullptr, 1152, 0, 0, 9},
       q1{dw1_b, bq_dw1, nullptr, 128, 0, 0, 1},
       q2{dw2_w, wq_dw2, nullptr, 1152, 0, 0, 9},
       q3{dw2_b, bq_dw2, nullptr, 128, 0, 0, 1},
       q4{pw1_w, nullptr, wc_pw1, 65536, 1, 8, 128},
       q5{pw1_b, bq_pw1, nullptr, 512, 0, 0, 1},
       q6{pw2_w, nullptr, wc_pw2, 65536, 1, 9, 512},
       q7{pw2_b, bq_pw2, nullptr, 128, 0, 0, 1},
       q8{up_w, nullptr, wc_up, 294912, 2, 10, 128},
       q9{up_b, bq_up, nullptr, 256, 0, 0, 1};
    wabsmax_kernel<<<dim3(32, 10), 256, 0, stream>>>(q0, q1, q2, q3, q4, q5, q6, q7, q8, q9, scal);
    wquant_kernel<<<dim3(32, 10), 256, 0, stream>>>(q0, q1, q2, q3, q4, q5, q6, q7, q8, q9, scal);
    corr_kernel<<<dim3(256, 2), 64, 0, stream>>>(pw2_w, up_w, scal, corrP2, corrU);

    // residual block 1 (dwconv1 also computes absmax(x) -> slot 0); grid-stride, few atomics
    dwconv_kernel<<<2048, 256, 0, stream>>>(x, wq_dw1, bq_dw1, Abuf, scal + 1, scal + 0);
    residual_kernel<<<2048, 256, 0, stream>>>((const float4*)Abuf, (const float4*)x,
                                              (float4*)Bbuf, scal, 1, 0, scal + 2);
    // residual block 2 -> i8 NHWC code planes
    dwconv_kernel<<<2048, 256, 0, stream>>>(Bbuf, wq_dw2, bq_dw2, Abuf, scal + 3, nullptr);
    residual2_codes_kernel<<<2048, 256, 0, stream>>>(Abuf, Bbuf, jcode, icode, scal);

    // pw1 (dual-plane exact GEMM): pass1 max -> slot4, pass2 shifted codes -> p1codes
    pwmfma_kernel<128, 256, true, 0><<<dim3(2048, 2), 256, 0, stream>>>(
        jcode, icode, wc_pw1, bq_pw1, nullptr, scal, nullptr, C4, 0, 8, 0, scal + 4);
    pwmfma_kernel<128, 256, true, 1><<<dim3(2048, 2), 256, 0, stream>>>(
        jcode, icode, wc_pw1, bq_pw1, p1codes, scal, nullptr, C4, 0, 8, 4, nullptr);

    // pw2: shifted input (corrP2), pass1 max -> slot5, pass2 shifted codes -> p2codes
    pwmfma_kernel<512, 128, false, 0><<<dim3(2048, 1), 256, 0, stream>>>(
        p1codes, nullptr, wc_pw2, bq_pw2, nullptr, scal, corrP2, Cc, 4, 9, 0, scal + 5);
    pwmfma_kernel<512, 128, false, 1><<<dim3(2048, 1), 256, 0, stream>>>(
        p1codes, nullptr, wc_pw2, bq_pw2, p2codes, scal, corrP2, Cc, 4, 9, 5, nullptr);

    // up 3x3 -> d_out fp32 + max slot6, then final quant in place
    conv3x3_mfma_kernel<<<2048, 256, 0, stream>>>(p2codes, wc_up, bq_up, out, scal, corrU, scal + 6);
    quant_inplace_kernel<<<4096, 256, 0, stream>>>((float4*)out, NOUT / 4, scal, 6);
}

// Round 11
// 477.283 us; speedup vs baseline: 1.8141x; 1.0357x over previous
//
#include <hip/hip_runtime.h>

#define EPSQ 1e-8f

typedef unsigned short u16;
typedef signed char i8;
typedef __attribute__((ext_vector_type(4))) int int4v;
typedef __attribute__((ext_vector_type(4))) unsigned int uint4v;

static constexpr int  Bn = 8, Cc = 128, Hh = 128, Ww = 128, HW = Hh * Ww; // 16384
static constexpr int  C4 = 512, CO = 256;
static constexpr long NX   = (long)Bn * Cc * HW;   // 16,777,216
static constexpr long NOUT = (long)Bn * CO * HW;   // 33,554,432

#define MFMAI8(a,b,c) __builtin_amdgcn_mfma_i32_16x16x64_i8(a,b,c,0,0,0)

__device__ __forceinline__ float ubits(unsigned u) { return __uint_as_float(u); }

__device__ __forceinline__ float4 fma4(float a, float4 b, float4 c) {
    float4 r;
    r.x = fmaf(a, b.x, c.x); r.y = fmaf(a, b.y, c.y);
    r.z = fmaf(a, b.z, c.z); r.w = fmaf(a, b.w, c.w);
    return r;
}

// ---------------- sharded max reduction ----------------
// Each logical max-slot = 16 cache lines (16 x 32 uints, 128B apart).
// Producers atomicMax into line (blockIdx & 15); consumers reduce all 16.

__device__ __forceinline__ float rdmax16(const unsigned* base) {
    float m = 0.f;
    #pragma unroll
    for (int i = 0; i < 16; i++) m = fmaxf(m, __uint_as_float(base[i * 32]));
    return m;
}

__device__ __forceinline__ void block_max_shard(float v, unsigned* base) {
    #pragma unroll
    for (int off = 32; off; off >>= 1) v = fmaxf(v, __shfl_down(v, off));
    __shared__ float sm[8];
    int lane = threadIdx.x & 63, wid = threadIdx.x >> 6;
    if (lane == 0) sm[wid] = v;
    __syncthreads();
    if (threadIdx.x == 0) {
        float m = sm[0];
        int nw = (blockDim.x + 63) >> 6;
        for (int i = 1; i < nw; i++) m = fmaxf(m, sm[i]);
        unsigned* slot = base + (blockIdx.x & 15) * 32;
        if (m > __uint_as_float(*(volatile unsigned*)slot))
            atomicMax(slot, __float_as_uint(m));
    }
    __syncthreads();
}

// variant with caller-provided LDS scratch (kernels with big static LDS)
__device__ __forceinline__ void block_max_shard2(float v, unsigned* base, float* sm) {
    #pragma unroll
    for (int off = 32; off; off >>= 1) v = fmaxf(v, __shfl_down(v, off));
    int lane = threadIdx.x & 63, wid = threadIdx.x >> 6;
    __syncthreads();
    if (lane == 0) sm[wid] = v;
    __syncthreads();
    if (threadIdx.x == 0) {
        float m = sm[0];
        int nw = (blockDim.x + 63) >> 6;
        for (int i = 1; i < nw; i++) m = fmaxf(m, sm[i]);
        unsigned* slot = base + (blockIdx.x & 15) * 32;
        if (m > __uint_as_float(*(volatile unsigned*)slot))
            atomicMax(slot, __float_as_uint(m));
    }
}

// plain single-slot version (weight absmax only; low contention)
__device__ __forceinline__ void block_max_atomic(float v, unsigned* slot) {
    #pragma unroll
    for (int off = 32; off; off >>= 1) v = fmaxf(v, __shfl_down(v, off));
    __shared__ float sm[8];
    int lane = threadIdx.x & 63, wid = threadIdx.x >> 6;
    if (lane == 0) sm[wid] = v;
    __syncthreads();
    if (threadIdx.x == 0) {
        float m = sm[0];
        int nw = (blockDim.x + 63) >> 6;
        for (int i = 1; i < nw; i++) m = fmaxf(m, sm[i]);
        if (m > __uint_as_float(*(volatile unsigned*)slot))
            atomicMax(slot, __float_as_uint(m));
    }
    __syncthreads();
}

// ---------------- weight fake-quant ----------------
// mode 0: fp32 dequant to dstF.
// mode 1: i8 codes packed for 16x16x64 MFMA: [otile][kb(64)][lane][16].
// mode 2: 3x3 (K=128): [otile][tap][kb][lane][16].
struct QW { const float* src; float* dstF; i8* dstC; int n; int mode; int slot; int kdim; };

__device__ __forceinline__ QW qw_select(const QW& q0, const QW& q1, const QW& q2, const QW& q3,
                                        const QW& q4, const QW& q5, const QW& q6, const QW& q7,
                                        const QW& q8, const QW& q9, int t) {
    switch (t) {
        case 0: return q0; case 1: return q1; case 2: return q2; case 3: return q3;
        case 4: return q4; case 5: return q5; case 6: return q6; case 7: return q7;
        case 8: return q8; default: return q9;
    }
}

__global__ void wabsmax_kernel(QW q0, QW q1, QW q2, QW q3, QW q4,
                               QW q5, QW q6, QW q7, QW q8, QW q9,
                               unsigned* __restrict__ scal) {
    QW q = qw_select(q0, q1, q2, q3, q4, q5, q6, q7, q8, q9, blockIdx.y);
    int i0 = blockIdx.x * blockDim.x + threadIdx.x;
    int str = gridDim.x * blockDim.x;
    float m = 0.f;
    for (int i = i0; i < q.n; i += str) m = fmaxf(m, fabsf(q.src[i]));
    block_max_atomic(m, scal + 16 + blockIdx.y);
}

__global__ void wquant_kernel(QW q0, QW q1, QW q2, QW q3, QW q4,
                              QW q5, QW q6, QW q7, QW q8, QW q9,
                              unsigned* __restrict__ scal) {
    QW q = qw_select(q0, q1, q2, q3, q4, q5, q6, q7, q8, q9, blockIdx.y);
    float s = fmaxf(ubits(scal[16 + blockIdx.y]), EPSQ) / 127.f;
    if (q.mode != 0 && blockIdx.x == 0 && threadIdx.x == 0) scal[q.slot] = __float_as_uint(s);
    int i0 = blockIdx.x * blockDim.x + threadIdx.x;
    int str = gridDim.x * blockDim.x;
    for (int i = i0; i < q.n; i += str) {
        float v = fminf(fmaxf(rintf(q.src[i] / s), -127.f), 127.f);
        int code = (int)v;
        if (q.mode == 0) q.dstF[i] = v * s;
        else if (q.mode == 1) {
            int o = i / q.kdim, k = i % q.kdim;
            int otile = o >> 4, r = o & 15, kb = k >> 6, qq = (k & 63) >> 4, e = k & 15;
            q.dstC[((otile * (q.kdim >> 6) + kb) * 64 + qq * 16 + r) * 16 + e] = (i8)code;
        } else {
            int o = i / 1152, rem = i % 1152, c = rem / 9, t = rem % 9;
            int otile = o >> 4, r = o & 15, kb = c >> 6, qq = (c & 63) >> 4, e = c & 15;
            q.dstC[(((otile * 9 + t) * 2 + kb) * 64 + qq * 16 + r) * 16 + e] = (i8)code;
        }
    }
}

// ---------------- shift-correction sums (atomic-free, 1 wave per output ch) ----------------

__global__ void corr_kernel(const float* __restrict__ pw2_w, const float* __restrict__ up_w,
                            const unsigned* __restrict__ scal,
                            int* __restrict__ corrP2, int* __restrict__ corrU) {
    int lane = threadIdx.x;           // 64 threads
    if (blockIdx.y == 0) {
        int o = blockIdx.x;
        if (o >= 128) return;
        float s = fmaxf(ubits(scal[16 + 6]), EPSQ) / 127.f;
        int sum = 0;
        for (int k = lane; k < 512; k += 64)
            sum += (int)fminf(fmaxf(rintf(pw2_w[o * 512 + k] / s), -127.f), 127.f);
        #pragma unroll
        for (int off = 32; off; off >>= 1) sum += __shfl_down(sum, off);
        if (lane == 0) corrP2[o] = sum;
    } else {
        int o = blockIdx.x;
        float s = fmaxf(ubits(scal[16 + 8]), EPSQ) / 127.f;
        int sum[3] = {0, 0, 0};
        for (int i = lane; i < 1152; i += 64) {
            int t = i % 9;
            int code = (int)fminf(fmaxf(rintf(up_w[o * 1152 + i] / s), -127.f), 127.f);
            sum[t / 3] += code;
        }
        #pragma unroll
        for (int r = 0; r < 3; r++) {
            int v = sum[r];
            #pragma unroll
            for (int off = 32; off; off >>= 1) v += __shfl_down(v, off);
            if (lane == 0) corrU[r * 256 + o] = v;
        }
    }
}

// ---------------- depthwise 3x3 (pad 1), fp32, vectorized float4, grid-stride ----------------

__global__ __launch_bounds__(256) void dwconv_kernel(
    const float* __restrict__ in, const float* __restrict__ wq,
    const float* __restrict__ bq, float* __restrict__ out,
    unsigned* msh, unsigned* xsh) {
    int tg = threadIdx.x & 31;        // col group: j0 = tg*4
    int rh = threadIdx.x >> 5;        // 0..7
    int j0 = tg * 4;
    const float4 z4 = {0.f, 0.f, 0.f, 0.f};
    float mm = 0.f, mx = 0.f;

    for (int tile = blockIdx.x; tile < Bn * Cc * 8; tile += gridDim.x) {
        int bc = tile >> 3, yt = tile & 7;
        int c  = bc & (Cc - 1);
        float w[9];
        #pragma unroll
        for (int k = 0; k < 9; k++) w[k] = wq[c * 9 + k];
        float bias = bq[c];
        const float* src = in + (long)bc * HW;
        float* dst = out + (long)bc * HW;
        int r0 = yt * 16 + rh * 2;

        float4 L[4], C[4], R[4];
        #pragma unroll
        for (int t = 0; t < 4; t++) {
            int row = r0 - 1 + t;
            if (row < 0 || row > 127) { L[t] = z4; C[t] = z4; R[t] = z4; continue; }
            const float* p = src + row * Ww + j0;
            float4 cv = *reinterpret_cast<const float4*>(p);
            C[t] = cv;
            L[t] = (j0 > 0)   ? *reinterpret_cast<const float4*>(p - 4) : z4;
            R[t] = (j0 < 124) ? *reinterpret_cast<const float4*>(p + 4) : z4;
            mx = fmaxf(mx, fmaxf(fmaxf(fabsf(cv.x), fabsf(cv.y)),
                                 fmaxf(fabsf(cv.z), fabsf(cv.w))));
        }

        #pragma unroll
        for (int rr = 0; rr < 2; rr++) {
            float4 acc = {bias, bias, bias, bias};
            #pragma unroll
            for (int t = 0; t < 3; t++) {
                float4 l = L[rr + t], cc = C[rr + t], r = R[rr + t];
                float4 wm1 = {l.w, cc.x, cc.y, cc.z};
                float4 wp1 = {cc.y, cc.z, cc.w, r.x};
                acc = fma4(w[t * 3 + 0], wm1, acc);
                acc = fma4(w[t * 3 + 1], cc,  acc);
                acc = fma4(w[t * 3 + 2], wp1, acc);
            }
            *reinterpret_cast<float4*>(dst + (r0 + rr) * Ww + j0) = acc;
            mm = fmaxf(mm, fmaxf(fmaxf(acc.x, acc.y), fmaxf(acc.z, acc.w)));
        }
    }
    block_max_shard(fmaxf(mm, 0.f), msh);
    if (xsh) block_max_shard(mx, xsh);
}

// ---------------- residual 1: r = fq(quant_relu(t)) + fq(x), fp32 out + max ----------------

__global__ void residual_kernel(const float4* __restrict__ t, const float4* __restrict__ xin,
                                float4* __restrict__ r, const unsigned* __restrict__ msh,
                                int mReluIdx, int mXIdx, unsigned* moutsh) {
    float s1  = fmaxf(rdmax16(msh + mReluIdx * 512), EPSQ) / 255.f;
    float mh  = 255.f * s1;
    float s1b = fmaxf(mh, EPSQ) / 127.f;
    float sx  = fmaxf(rdmax16(msh + mXIdx * 512), EPSQ) / 127.f;
    long i0 = (long)blockIdx.x * blockDim.x + threadIdx.x;
    long str = (long)gridDim.x * blockDim.x;
    long n4 = NX >> 2;
    float mm = 0.f;
    for (long i = i0; i < n4; i += str) {
        float4 tv = t[i];
        float4 xv = xin[i];
        float o[4];
        float tc[4] = {tv.x, tv.y, tv.z, tv.w};
        float xc[4] = {xv.x, xv.y, xv.z, xv.w};
        #pragma unroll
        for (int k = 0; k < 4; k++) {
            float h  = fminf(rintf(fmaxf(tc[k], 0.f) / s1), 255.f) * s1;
            float hq = fminf(fmaxf(rintf(h / s1b), -127.f), 127.f) * s1b;
            float xq = fminf(fmaxf(rintf(xc[k] / sx), -127.f), 127.f) * sx;
            o[k] = hq + xq;
            mm = fmaxf(mm, fabsf(o[k]));
        }
        float4 ov = {o[0], o[1], o[2], o[3]};
        r[i] = ov;
    }
    if (moutsh) block_max_shard(mm, moutsh);
}

// ---------------- residual 2: emit NHWC i8 code planes (j from dw2-path, i from r1) ----------------

__global__ __launch_bounds__(256) void residual2_codes_kernel(
    const float* __restrict__ t2, const float* __restrict__ r1,
    i8* __restrict__ jc, i8* __restrict__ ic, const unsigned* __restrict__ msh) {
    float s1  = fmaxf(rdmax16(msh + 3 * 512), EPSQ) / 255.f;
    float s1b = fmaxf(255.f * s1, EPSQ) / 127.f;
    float sx  = fmaxf(rdmax16(msh + 2 * 512), EPSQ) / 127.f;
    int b = blockIdx.x >> 8;
    long px0 = (long)(blockIdx.x & 255) * 64;
    __shared__ __align__(16) i8 lj[64 * 128];
    __shared__ __align__(16) i8 li[64 * 128];
    int px = threadIdx.x & 63, cq = threadIdx.x >> 6;
    for (int it = 0; it < 8; it++) {
        int cb = it * 16 + cq * 4;
        unsigned pj = 0, pi = 0;
        #pragma unroll
        for (int e = 0; e < 4; e++) {
            int c = cb + e;
            long g = ((long)b * Cc + c) * HW + px0 + px;
            float t = t2[g], x = r1[g];
            float hq = fminf(rintf(fmaxf(t, 0.f) / s1), 255.f) * s1;
            int j = (int)fminf(fmaxf(rintf(hq / s1b), -127.f), 127.f);
            int i = (int)fminf(fmaxf(rintf(x / sx), -127.f), 127.f);
            pj |= ((unsigned)(unsigned char)(i8)j) << (8 * e);
            pi |= ((unsigned)(unsigned char)(i8)i) << (8 * e);
        }
        int ad = (px * 128 + cb) ^ ((px & 7) << 4);
        *reinterpret_cast<int*>(lj + ad) = (int)pj;
        *reinterpret_cast<int*>(li + ad) = (int)pi;
    }
    __syncthreads();
    for (int s = threadIdx.x; s < 512; s += 256) {
        int px2 = s >> 3, sl = s & 7;
        int ad = (px2 * 128 + sl * 16) ^ ((px2 & 7) << 4);
        long dst = ((long)b * HW + px0 + px2) * 128 + sl * 16;
        *reinterpret_cast<uint4v*>(jc + dst) = *reinterpret_cast<uint4v*>(lj + ad);
        *reinterpret_cast<uint4v*>(ic + dst) = *reinterpret_cast<uint4v*>(li + ad);
    }
}

// ---------------- pointwise i8-MFMA GEMM over integer codes ----------------
// MODE 0: relu max only (sharded). MODE 1: write quantized i8 codes (shifted -128) NHWC.
template<int K, int OB, bool DUAL, int MODE>
__global__ __launch_bounds__(256) void pwmfma_kernel(
    const i8* __restrict__ bc0, const i8* __restrict__ bc1,
    const i8* __restrict__ wc, const float* __restrict__ bias,
    i8* __restrict__ outc, const unsigned* __restrict__ scal,
    const unsigned* __restrict__ msh, const int* __restrict__ corrI,
    int O_total, int sInSlot, int sWSlot, int sOutSlot, unsigned* moutsh) {

    constexpr int F = OB / 64;                    // o-frags (of 16) per wave
    constexpr int KB = K / 64;
    constexpr int LSZ = (DUAL ? 2 : 1) * 64 * K;
    __shared__ __align__(16) i8 lds[LSZ];
    int lane = threadIdx.x & 63, wv = threadIdx.x >> 6;
    int lane15 = lane & 15;
    int b = blockIdx.x >> 8;
    long px0 = (long)(blockIdx.x & 255) * 64;
    long pixbase = (long)b * HW + px0;
    int oB = blockIdx.y * OB;
    int oW = wv * (OB / 4);

    for (int s = threadIdx.x; s < 4 * K; s += 256) {        // 64 px * K/16 chunks
        int px = s / (K / 16), cs = s % (K / 16);
        long gsrc = (pixbase + px) * K + cs * 16;
        int addr = (px * K + cs * 16) ^ ((px & 7) << 4);
        *reinterpret_cast<uint4v*>(lds + addr) = *reinterpret_cast<const uint4v*>(bc0 + gsrc);
        if (DUAL)
            *reinterpret_cast<uint4v*>(lds + 64 * K + addr) =
                *reinterpret_cast<const uint4v*>(bc1 + gsrc);
    }
    __syncthreads();

    const int4v z4 = {0, 0, 0, 0};
    int4v accA[F][4], accB[F][4];
    #pragma unroll
    for (int i = 0; i < F; i++)
        #pragma unroll
        for (int j = 0; j < 4; j++) { accA[i][j] = z4; accB[i][j] = z4; }

    const i8* wpack = wc + ((long)((oB + oW) >> 4) * KB) * 1024 + lane * 16;

    #pragma unroll
    for (int kb = 0; kb < KB; kb++) {
        int4v a[F];
        #pragma unroll
        for (int f = 0; f < F; f++)
            a[f] = *reinterpret_cast<const int4v*>(wpack + ((long)f * KB + kb) * 1024);
        #pragma unroll
        for (int fn = 0; fn < 4; fn++) {
            int col = fn * 16 + lane15;
            int ad = (col * K + kb * 64 + (lane >> 4) * 16) ^ ((col & 7) << 4);
            int4v b0 = *reinterpret_cast<const int4v*>(lds + ad);
            #pragma unroll
            for (int f = 0; f < F; f++) accA[f][fn] = MFMAI8(a[f], b0, accA[f][fn]);
            if (DUAL) {
                int4v b1 = *reinterpret_cast<const int4v*>(lds + 64 * K + ad);
                #pragma unroll
                for (int f = 0; f < F; f++) accB[f][fn] = MFMAI8(a[f], b1, accB[f][fn]);
            }
        }
    }

    float sW = ubits(scal[sWSlot]);
    float sA, sB_;
    if (DUAL) {
        float s1 = fmaxf(rdmax16(msh + 3 * 512), EPSQ) / 255.f;
        sA  = fmaxf(255.f * s1, EPSQ) / 127.f;     // s1b (j codes)
        sB_ = fmaxf(rdmax16(msh + 2 * 512), EPSQ) / 127.f; // sx (i codes)
    } else {
        sA = fmaxf(rdmax16(msh + sInSlot * 512), EPSQ) / 255.f;
        sB_ = 0.f;
    }

    if (MODE == 0) {
        float mm = 0.f;
        #pragma unroll
        for (int f = 0; f < F; f++)
        #pragma unroll
        for (int fn = 0; fn < 4; fn++)
        #pragma unroll
        for (int r = 0; r < 4; r++) {
            int o = oB + oW + f * 16 + (lane >> 4) * 4 + r;
            float av;
            if (DUAL) av = sA * (float)accA[f][fn][r] + sB_ * (float)accB[f][fn][r];
            else      av = sA * (float)(accA[f][fn][r] + (corrI[o] << 7));
            float v = fmaxf(sW * av + bias[o], 0.f);
            mm = fmaxf(mm, v);
        }
        block_max_shard2(mm, moutsh, reinterpret_cast<float*>(lds));
    } else {
        float sOut = fmaxf(rdmax16(msh + sOutSlot * 512), EPSQ) / 255.f;
        __syncthreads();
        #pragma unroll
        for (int f = 0; f < F; f++)
        #pragma unroll
        for (int fn = 0; fn < 4; fn++) {
            int orow0 = oW + f * 16 + (lane >> 4) * 4;
            unsigned pk = 0;
            #pragma unroll
            for (int r = 0; r < 4; r++) {
                int o = oB + orow0 + r;
                float av;
                if (DUAL) av = sA * (float)accA[f][fn][r] + sB_ * (float)accB[f][fn][r];
                else      av = sA * (float)(accA[f][fn][r] + (corrI[o] << 7));
                float v = fmaxf(sW * av + bias[o], 0.f);
                int code = (int)fminf(rintf(v / sOut), 255.f) - 128;   // shifted storage
                pk |= ((unsigned)(unsigned char)(i8)code) << (8 * r);
            }
            int pxl = fn * 16 + lane15;
            int ad = (pxl * OB + orow0) ^ ((pxl & 7) << 4);
            *reinterpret_cast<int*>(lds + ad) = (int)pk;
        }
        __syncthreads();
        constexpr int CH = OB / 16;       // 16B chunks per px row
        for (int s = threadIdx.x; s < 64 * CH; s += 256) {
            int px = s / CH, sl = s % CH;
            int ad = (px * OB + sl * 16) ^ ((px & 7) << 4);
            *reinterpret_cast<uint4v*>(outc + (pixbase + px) * O_total + oB + sl * 16) =
                *reinterpret_cast<uint4v*>(lds + ad);
        }
    }
}

// ---------------- 3x3 conv 128->256 i8-MFMA, fp32 NCHW out + sharded max ----------------

__global__ __launch_bounds__(256) void conv3x3_mfma_kernel(
    const i8* __restrict__ xc,    // NHWC shifted codes [B*HW][128]
    const i8* __restrict__ wc,    // packed [16][9][2][64][16]
    const float* __restrict__ bias, float* __restrict__ out,
    const unsigned* __restrict__ scal, const unsigned* __restrict__ msh,
    const int* __restrict__ corrU, unsigned* moutsh) {

    __shared__ __align__(16) i8 lds[3 * 66 * 128];
    int lane = threadIdx.x & 63, wv = threadIdx.x >> 6;
    int lane15 = lane & 15;
    int bx = blockIdx.x;
    int b = bx >> 8, h = (bx >> 1) & 127, wseg = bx & 1;
    int oW = wv * 64;

    // stage 3 rows x 66 cols x 128 ch (i8); OOB cols = 0x80 (shifted zero)
    for (int s = threadIdx.x; s < 3 * 66 * 8; s += 256) {
        int row = s / (66 * 8), rem = s % (66 * 8), col = rem >> 3, sl = rem & 7;
        int hh = h + row - 1;
        if (hh < 0 || hh > 127) continue;      // row's taps skipped entirely
        int wgl = wseg * 64 + col - 1;
        uint4v v = {0x80808080u, 0x80808080u, 0x80808080u, 0x80808080u};
        if (wgl >= 0 && wgl <= 127) {
            long pix = (long)b * HW + (long)hh * 128 + wgl;
            v = *reinterpret_cast<const uint4v*>(xc + pix * 128 + sl * 16);
        }
        int addr = ((row * 66 + col) * 128 + sl * 16) ^ ((col & 7) << 4);
        *reinterpret_cast<uint4v*>(lds + addr) = v;
    }
    __syncthreads();

    const int4v z4 = {0, 0, 0, 0};
    int4v acc[4][4];
    #pragma unroll
    for (int i = 0; i < 4; i++)
        #pragma unroll
        for (int j = 0; j < 4; j++) acc[i][j] = z4;

    const i8* wpack = wc + (long)(wv * 4) * 18 * 1024 + lane * 16;  // otile0 = wv*4
    for (int di = 0; di < 3; di++) {
        int hh = h + di - 1;
        if (hh < 0 || hh > 127) continue;      // block-uniform
        for (int dj = 0; dj < 3; dj++) {
            int tap = di * 3 + dj;
            #pragma unroll
            for (int kb = 0; kb < 2; kb++) {
                int4v a[4];
                #pragma unroll
                for (int f = 0; f < 4; f++)
                    a[f] = *reinterpret_cast<const int4v*>(
                        wpack + ((long)(f * 9 + tap) * 2 + kb) * 1024);
                int4v bb[4];
                #pragma unroll
                for (int fn = 0; fn < 4; fn++) {
                    int col = fn * 16 + lane15 + dj;
                    bb[fn] = *reinterpret_cast<const int4v*>(lds +
                        (((di * 66 + col) * 128 + kb * 64 + (lane >> 4) * 16) ^ ((col & 7) << 4)));
                }
                #pragma unroll
                for (int f = 0; f < 4; f++)
                    #pragma unroll
                    for (int fn = 0; fn < 4; fn++)
                        acc[f][fn] = MFMAI8(a[f], bb[fn], acc[f][fn]);
            }
        }
    }

    float s5 = fmaxf(rdmax16(msh + 5 * 512), EPSQ) / 255.f;
    float sc = ubits(scal[10]) * s5;
    float mm = 0.f;
    #pragma unroll
    for (int f = 0; f < 4; f++)
    #pragma unroll
    for (int r = 0; r < 4; r++) {
        int o = oW + f * 16 + (lane >> 4) * 4 + r;
        int csum = corrU[256 + o];
        if (h > 0)   csum += corrU[o];
        if (h < 127) csum += corrU[512 + o];
        #pragma unroll
        for (int fn = 0; fn < 4; fn++) {
            int px = wseg * 64 + fn * 16 + lane15;
            int ai = acc[f][fn][r] + (csum << 7);
            float v = fmaxf(sc * (float)ai + bias[o], 0.f);
            mm = fmaxf(mm, v);
            out[((long)(b * CO + o)) * HW + h * 128 + px] = v;
        }
    }
    block_max_shard2(mm, moutsh, reinterpret_cast<float*>(lds));
}

// ---------------- in-place quant of a relu'd tensor (255 levels) ----------------

__global__ void quant_inplace_kernel(float4* __restrict__ p, long n4,
                                     const unsigned* __restrict__ msh, int idx) {
    float s = fmaxf(rdmax16(msh + idx * 512), EPSQ) / 255.f;
    long i0 = (long)blockIdx.x * blockDim.x + threadIdx.x;
    long str = (long)gridDim.x * blockDim.x;
    for (long i = i0; i < n4; i += str) {
        float4 v = p[i];
        v.x = fminf(rintf(v.x / s), 255.f) * s;
        v.y = fminf(rintf(v.y / s), 255.f) * s;
        v.z = fminf(rintf(v.z / s), 255.f) * s;
        v.w = fminf(rintf(v.w / s), 255.f) * s;
        p[i] = v;
    }
}

// ---------------- launch ----------------

extern "C" void kernel_launch(void* const* d_in, const int* in_sizes, int n_in,
                              void* d_out, int out_size, void* d_ws, size_t ws_size,
                              hipStream_t stream) {
    (void)in_sizes; (void)n_in; (void)out_size; (void)ws_size;
    const float* x     = (const float*)d_in[0];
    const float* dw1_w = (const float*)d_in[1];
    const float* dw1_b = (const float*)d_in[2];
    const float* dw2_w = (const float*)d_in[3];
    const float* dw2_b = (const float*)d_in[4];
    const float* pw1_w = (const float*)d_in[5];
    const float* pw1_b = (const float*)d_in[6];
    const float* pw2_w = (const float*)d_in[7];
    const float* pw2_b = (const float*)d_in[8];
    const float* up_w  = (const float*)d_in[9];
    const float* up_b  = (const float*)d_in[10];
    float* out = (float*)d_out;
    float* ws  = (float*)d_ws;

    // ws layout (float units):
    // [0, NX)          Abuf fp32          (later: p1codes i8)
    // [NX, 2NX)        Bbuf fp32
    // [2NX, 2NX+NX/4)  jcode i8           (later: p2codes i8)
    // [2NX+NX/4, 2NX+NX/2) icode i8
    // [3NX, ...)       weight area + scal + corr + sharded max slots
    float* Abuf = ws;
    float* Bbuf = ws + NX;
    i8*    jcode   = (i8*)(ws + 2 * NX);
    i8*    icode   = jcode + NX;
    i8*    p1codes = (i8*)ws;
    i8*    p2codes = (i8*)(ws + 2 * NX);

    float* wbase  = ws + 3 * NX;
    float* wq_dw1 = wbase;          float* bq_dw1 = wbase + 1152;
    float* wq_dw2 = wbase + 1280;   float* bq_dw2 = wbase + 2432;
    float* bq_pw1 = wbase + 2560;
    float* bq_pw2 = wbase + 3072;
    float* bq_up  = wbase + 3200;
    i8*    wc_pw1 = (i8*)(wbase + 3456);    // 65536 B
    i8*    wc_pw2 = (i8*)(wbase + 19840);   // 65536 B
    i8*    wc_up  = (i8*)(wbase + 36224);   // 294912 B
    unsigned* scal = (unsigned*)(wbase + 109952);   // 32: weight scales + absmax
    int*   corrU  = (int*)(wbase + 109984);   // [3][256]
    int*   corrP2 = (int*)(wbase + 110752);   // [128]
    unsigned* msh = (unsigned*)(wbase + 110880); // 7 slots x 16 lines x 32 uints
    // shard slots: 0 SX | 1 M1 | 2 MR1 | 3 M2 | 4 M3(pw1 relu) | 5 M4(pw2 relu) | 6 M5(up relu)

    (void)hipMemsetAsync(scal, 0, (32 + 768 + 128 + 7 * 512) * sizeof(unsigned), stream);

    QW q0{dw1_w, wq_dw1, nullptr, 1152, 0, 0, 9},
       q1{dw1_b, bq_dw1, nullptr, 128, 0, 0, 1},
       q2{dw2_w, wq_dw2, nullptr, 1152, 0, 0, 9},
       q3{dw2_b, bq_dw2, nullptr, 128, 0, 0, 1},
       q4{pw1_w, nullptr, wc_pw1, 65536, 1, 8, 128},
       q5{pw1_b, bq_pw1, nullptr, 512, 0, 0, 1},
       q6{pw2_w, nullptr, wc_pw2, 65536, 1, 9, 512},
       q7{pw2_b, bq_pw2, nullptr, 128, 0, 0, 1},
       q8{up_w, nullptr, wc_up, 294912, 2, 10, 128},
       q9{up_b, bq_up, nullptr, 256, 0, 0, 1};
    wabsmax_kernel<<<dim3(32, 10), 256, 0, stream>>>(q0, q1, q2, q3, q4, q5, q6, q7, q8, q9, scal);
    wquant_kernel<<<dim3(32, 10), 256, 0, stream>>>(q0, q1, q2, q3, q4, q5, q6, q7, q8, q9, scal);
    corr_kernel<<<dim3(256, 2), 64, 0, stream>>>(pw2_w, up_w, scal, corrP2, corrU);

    // residual block 1 (dwconv1 also computes absmax(x) -> shard slot 0)
    dwconv_kernel<<<2048, 256, 0, stream>>>(x, wq_dw1, bq_dw1, Abuf, msh + 1 * 512, msh + 0 * 512);
    residual_kernel<<<2048, 256, 0, stream>>>((const float4*)Abuf, (const float4*)x,
                                              (float4*)Bbuf, msh, 1, 0, msh + 2 * 512);
    // residual block 2 -> i8 NHWC code planes
    dwconv_kernel<<<2048, 256, 0, stream>>>(Bbuf, wq_dw2, bq_dw2, Abuf, msh + 3 * 512, nullptr);
    residual2_codes_kernel<<<2048, 256, 0, stream>>>(Abuf, Bbuf, jcode, icode, msh);

    // pw1 (dual-plane exact GEMM): pass1 max -> shard 4, pass2 shifted codes -> p1codes
    pwmfma_kernel<128, 256, true, 0><<<dim3(2048, 2), 256, 0, stream>>>(
        jcode, icode, wc_pw1, bq_pw1, nullptr, scal, msh, nullptr, C4, 0, 8, 0, msh + 4 * 512);
    pwmfma_kernel<128, 256, true, 1><<<dim3(2048, 2), 256, 0, stream>>>(
        jcode, icode, wc_pw1, bq_pw1, p1codes, scal, msh, nullptr, C4, 0, 8, 4, nullptr);

    // pw2: shifted input (corrP2), pass1 max -> shard 5, pass2 shifted codes -> p2codes
    pwmfma_kernel<512, 128, false, 0><<<dim3(2048, 1), 256, 0, stream>>>(
        p1codes, nullptr, wc_pw2, bq_pw2, nullptr, scal, msh, corrP2, Cc, 4, 9, 0, msh + 5 * 512);
    pwmfma_kernel<512, 128, false, 1><<<dim3(2048, 1), 256, 0, stream>>>(
        p1codes, nullptr, wc_pw2, bq_pw2, p2codes, scal, msh, corrP2, Cc, 4, 9, 5, nullptr);

    // up 3x3 -> d_out fp32 + shard 6 max, then final quant in place
    conv3x3_mfma_kernel<<<2048, 256, 0, stream>>>(p2codes, wc_up, bq_up, out, scal, msh,
                                                  corrU, msh + 6 * 512);
    quant_inplace_kernel<<<4096, 256, 0, stream>>>((float4*)out, NOUT / 4, msh, 6);
}

// Round 12
// 475.397 us; speedup vs baseline: 1.8213x; 1.0040x over previous
//
#include <hip/hip_runtime.h>

#define EPSQ 1e-8f

typedef unsigned short u16;
typedef signed char i8;
typedef __attribute__((ext_vector_type(4))) int int4v;
typedef __attribute__((ext_vector_type(16))) int int16v;
typedef __attribute__((ext_vector_type(4))) unsigned int uint4v;

static constexpr int  Bn = 8, Cc = 128, Hh = 128, Ww = 128, HW = Hh * Ww; // 16384
static constexpr int  C4 = 512, CO = 256;
static constexpr long NX   = (long)Bn * Cc * HW;   // 16,777,216
static constexpr long NOUT = (long)Bn * CO * HW;   // 33,554,432

#define MFMAI8(a,b,c)   __builtin_amdgcn_mfma_i32_16x16x64_i8(a,b,c,0,0,0)
#define MFMAI832(a,b,c) __builtin_amdgcn_mfma_i32_32x32x32_i8(a,b,c,0,0,0)

__device__ __forceinline__ float ubits(unsigned u) { return __uint_as_float(u); }

__device__ __forceinline__ float4 fma4(float a, float4 b, float4 c) {
    float4 r;
    r.x = fmaf(a, b.x, c.x); r.y = fmaf(a, b.y, c.y);
    r.z = fmaf(a, b.z, c.z); r.w = fmaf(a, b.w, c.w);
    return r;
}

// ---------------- sharded max reduction ----------------
// Each logical max-slot = 16 cache lines (16 x 32 uints, 128B apart).

__device__ __forceinline__ float rdmax16(const unsigned* base) {
    float m = 0.f;
    #pragma unroll
    for (int i = 0; i < 16; i++) m = fmaxf(m, __uint_as_float(base[i * 32]));
    return m;
}

__device__ __forceinline__ void block_max_shard(float v, unsigned* base) {
    #pragma unroll
    for (int off = 32; off; off >>= 1) v = fmaxf(v, __shfl_down(v, off));
    __shared__ float sm[8];
    int lane = threadIdx.x & 63, wid = threadIdx.x >> 6;
    if (lane == 0) sm[wid] = v;
    __syncthreads();
    if (threadIdx.x == 0) {
        float m = sm[0];
        int nw = (blockDim.x + 63) >> 6;
        for (int i = 1; i < nw; i++) m = fmaxf(m, sm[i]);
        unsigned* slot = base + (blockIdx.x & 15) * 32;
        if (m > __uint_as_float(*(volatile unsigned*)slot))
            atomicMax(slot, __float_as_uint(m));
    }
    __syncthreads();
}

__device__ __forceinline__ void block_max_shard2(float v, unsigned* base, float* sm) {
    #pragma unroll
    for (int off = 32; off; off >>= 1) v = fmaxf(v, __shfl_down(v, off));
    int lane = threadIdx.x & 63, wid = threadIdx.x >> 6;
    __syncthreads();
    if (lane == 0) sm[wid] = v;
    __syncthreads();
    if (threadIdx.x == 0) {
        float m = sm[0];
        int nw = (blockDim.x + 63) >> 6;
        for (int i = 1; i < nw; i++) m = fmaxf(m, sm[i]);
        unsigned* slot = base + (blockIdx.x & 15) * 32;
        if (m > __uint_as_float(*(volatile unsigned*)slot))
            atomicMax(slot, __float_as_uint(m));
    }
}

// plain single-slot version (weight absmax only; low contention)
__device__ __forceinline__ void block_max_atomic(float v, unsigned* slot) {
    #pragma unroll
    for (int off = 32; off; off >>= 1) v = fmaxf(v, __shfl_down(v, off));
    __shared__ float sm[8];
    int lane = threadIdx.x & 63, wid = threadIdx.x >> 6;
    if (lane == 0) sm[wid] = v;
    __syncthreads();
    if (threadIdx.x == 0) {
        float m = sm[0];
        int nw = (blockDim.x + 63) >> 6;
        for (int i = 1; i < nw; i++) m = fmaxf(m, sm[i]);
        if (m > __uint_as_float(*(volatile unsigned*)slot))
            atomicMax(slot, __float_as_uint(m));
    }
    __syncthreads();
}

// ---------------- weight fake-quant ----------------
// mode 0: fp32 dequant to dstF.
// mode 1: i8 codes packed for 16x16x64 MFMA: [otile16][kb(64)][lane][16],
//         o=otile*16+(lane&15), k=kb*64+(lane>>4)*16+e.
// mode 2: 3x3 (K=128) packed for 32x32x32 MFMA: [otile32][tap][kb(32)][lane][16],
//         o=otile*32+(lane&31), k=kb*32+(lane>>5)*16+e.
struct QW { const float* src; float* dstF; i8* dstC; int n; int mode; int slot; int kdim; };

__device__ __forceinline__ QW qw_select(const QW& q0, const QW& q1, const QW& q2, const QW& q3,
                                        const QW& q4, const QW& q5, const QW& q6, const QW& q7,
                                        const QW& q8, const QW& q9, int t) {
    switch (t) {
        case 0: return q0; case 1: return q1; case 2: return q2; case 3: return q3;
        case 4: return q4; case 5: return q5; case 6: return q6; case 7: return q7;
        case 8: return q8; default: return q9;
    }
}

__global__ void wabsmax_kernel(QW q0, QW q1, QW q2, QW q3, QW q4,
                               QW q5, QW q6, QW q7, QW q8, QW q9,
                               unsigned* __restrict__ scal) {
    QW q = qw_select(q0, q1, q2, q3, q4, q5, q6, q7, q8, q9, blockIdx.y);
    int i0 = blockIdx.x * blockDim.x + threadIdx.x;
    int str = gridDim.x * blockDim.x;
    float m = 0.f;
    for (int i = i0; i < q.n; i += str) m = fmaxf(m, fabsf(q.src[i]));
    block_max_atomic(m, scal + 16 + blockIdx.y);
}

__global__ void wquant_kernel(QW q0, QW q1, QW q2, QW q3, QW q4,
                              QW q5, QW q6, QW q7, QW q8, QW q9,
                              unsigned* __restrict__ scal) {
    QW q = qw_select(q0, q1, q2, q3, q4, q5, q6, q7, q8, q9, blockIdx.y);
    float s = fmaxf(ubits(scal[16 + blockIdx.y]), EPSQ) / 127.f;
    if (q.mode != 0 && blockIdx.x == 0 && threadIdx.x == 0) scal[q.slot] = __float_as_uint(s);
    int i0 = blockIdx.x * blockDim.x + threadIdx.x;
    int str = gridDim.x * blockDim.x;
    for (int i = i0; i < q.n; i += str) {
        float v = fminf(fmaxf(rintf(q.src[i] / s), -127.f), 127.f);
        int code = (int)v;
        if (q.mode == 0) q.dstF[i] = v * s;
        else if (q.mode == 1) {
            int o = i / q.kdim, k = i % q.kdim;
            int otile = o >> 4, r = o & 15, kb = k >> 6, qq = (k & 63) >> 4, e = k & 15;
            q.dstC[((otile * (q.kdim >> 6) + kb) * 64 + qq * 16 + r) * 16 + e] = (i8)code;
        } else {
            int o = i / 1152, rem = i % 1152, c = rem / 9, t = rem % 9;
            int otile = o >> 5, r = o & 31, kb = c >> 5, qq = (c & 31) >> 4, e = c & 15;
            q.dstC[(((otile * 9 + t) * 4 + kb) * 64 + qq * 32 + r) * 16 + e] = (i8)code;
        }
    }
}

// ---------------- shift-correction sums (atomic-free, 1 wave per output ch) ----------------

__global__ void corr_kernel(const float* __restrict__ pw2_w, const float* __restrict__ up_w,
                            const unsigned* __restrict__ scal,
                            int* __restrict__ corrP2, int* __restrict__ corrU) {
    int lane = threadIdx.x;           // 64 threads
    if (blockIdx.y == 0) {
        int o = blockIdx.x;
        if (o >= 128) return;
        float s = fmaxf(ubits(scal[16 + 6]), EPSQ) / 127.f;
        int sum = 0;
        for (int k = lane; k < 512; k += 64)
            sum += (int)fminf(fmaxf(rintf(pw2_w[o * 512 + k] / s), -127.f), 127.f);
        #pragma unroll
        for (int off = 32; off; off >>= 1) sum += __shfl_down(sum, off);
        if (lane == 0) corrP2[o] = sum;
    } else {
        int o = blockIdx.x;
        float s = fmaxf(ubits(scal[16 + 8]), EPSQ) / 127.f;
        int sum[3] = {0, 0, 0};
        for (int i = lane; i < 1152; i += 64) {
            int t = i % 9;
            int code = (int)fminf(fmaxf(rintf(up_w[o * 1152 + i] / s), -127.f), 127.f);
            sum[t / 3] += code;
        }
        #pragma unroll
        for (int r = 0; r < 3; r++) {
            int v = sum[r];
            #pragma unroll
            for (int off = 32; off; off >>= 1) v += __shfl_down(v, off);
            if (lane == 0) corrU[r * 256 + o] = v;
        }
    }
}

// ---------------- depthwise 3x3 (pad 1), fp32, vectorized float4, grid-stride ----------------

__global__ __launch_bounds__(256) void dwconv_kernel(
    const float* __restrict__ in, const float* __restrict__ wq,
    const float* __restrict__ bq, float* __restrict__ out,
    unsigned* msh, unsigned* xsh) {
    int tg = threadIdx.x & 31;        // col group: j0 = tg*4
    int rh = threadIdx.x >> 5;        // 0..7
    int j0 = tg * 4;
    const float4 z4 = {0.f, 0.f, 0.f, 0.f};
    float mm = 0.f, mx = 0.f;

    for (int tile = blockIdx.x; tile < Bn * Cc * 8; tile += gridDim.x) {
        int bc = tile >> 3, yt = tile & 7;
        int c  = bc & (Cc - 1);
        float w[9];
        #pragma unroll
        for (int k = 0; k < 9; k++) w[k] = wq[c * 9 + k];
        float bias = bq[c];
        const float* src = in + (long)bc * HW;
        float* dst = out + (long)bc * HW;
        int r0 = yt * 16 + rh * 2;

        float4 L[4], C[4], R[4];
        #pragma unroll
        for (int t = 0; t < 4; t++) {
            int row = r0 - 1 + t;
            if (row < 0 || row > 127) { L[t] = z4; C[t] = z4; R[t] = z4; continue; }
            const float* p = src + row * Ww + j0;
            float4 cv = *reinterpret_cast<const float4*>(p);
            C[t] = cv;
            L[t] = (j0 > 0)   ? *reinterpret_cast<const float4*>(p - 4) : z4;
            R[t] = (j0 < 124) ? *reinterpret_cast<const float4*>(p + 4) : z4;
            mx = fmaxf(mx, fmaxf(fmaxf(fabsf(cv.x), fabsf(cv.y)),
                                 fmaxf(fabsf(cv.z), fabsf(cv.w))));
        }

        #pragma unroll
        for (int rr = 0; rr < 2; rr++) {
            float4 acc = {bias, bias, bias, bias};
            #pragma unroll
            for (int t = 0; t < 3; t++) {
                float4 l = L[rr + t], cc = C[rr + t], r = R[rr + t];
                float4 wm1 = {l.w, cc.x, cc.y, cc.z};
                float4 wp1 = {cc.y, cc.z, cc.w, r.x};
                acc = fma4(w[t * 3 + 0], wm1, acc);
                acc = fma4(w[t * 3 + 1], cc,  acc);
                acc = fma4(w[t * 3 + 2], wp1, acc);
            }
            *reinterpret_cast<float4*>(dst + (r0 + rr) * Ww + j0) = acc;
            mm = fmaxf(mm, fmaxf(fmaxf(acc.x, acc.y), fmaxf(acc.z, acc.w)));
        }
    }
    block_max_shard(fmaxf(mm, 0.f), msh);
    if (xsh) block_max_shard(mx, xsh);
}

// ---------------- residual 1: r = fq(quant_relu(t)) + fq(x), fp32 out + max ----------------

__global__ void residual_kernel(const float4* __restrict__ t, const float4* __restrict__ xin,
                                float4* __restrict__ r, const unsigned* __restrict__ msh,
                                int mReluIdx, int mXIdx, unsigned* moutsh) {
    float s1  = fmaxf(rdmax16(msh + mReluIdx * 512), EPSQ) / 255.f;
    float mh  = 255.f * s1;
    float s1b = fmaxf(mh, EPSQ) / 127.f;
    float sx  = fmaxf(rdmax16(msh + mXIdx * 512), EPSQ) / 127.f;
    long i0 = (long)blockIdx.x * blockDim.x + threadIdx.x;
    long str = (long)gridDim.x * blockDim.x;
    long n4 = NX >> 2;
    float mm = 0.f;
    for (long i = i0; i < n4; i += str) {
        float4 tv = t[i];
        float4 xv = xin[i];
        float o[4];
        float tc[4] = {tv.x, tv.y, tv.z, tv.w};
        float xc[4] = {xv.x, xv.y, xv.z, xv.w};
        #pragma unroll
        for (int k = 0; k < 4; k++) {
            float h  = fminf(rintf(fmaxf(tc[k], 0.f) / s1), 255.f) * s1;
            float hq = fminf(fmaxf(rintf(h / s1b), -127.f), 127.f) * s1b;
            float xq = fminf(fmaxf(rintf(xc[k] / sx), -127.f), 127.f) * sx;
            o[k] = hq + xq;
            mm = fmaxf(mm, fabsf(o[k]));
        }
        float4 ov = {o[0], o[1], o[2], o[3]};
        r[i] = ov;
    }
    if (moutsh) block_max_shard(mm, moutsh);
}

// ---------------- residual 2: emit NHWC i8 code planes (j from dw2-path, i from r1) ----------------

__global__ __launch_bounds__(256) void residual2_codes_kernel(
    const float* __restrict__ t2, const float* __restrict__ r1,
    i8* __restrict__ jc, i8* __restrict__ ic, const unsigned* __restrict__ msh) {
    float s1  = fmaxf(rdmax16(msh + 3 * 512), EPSQ) / 255.f;
    float s1b = fmaxf(255.f * s1, EPSQ) / 127.f;
    float sx  = fmaxf(rdmax16(msh + 2 * 512), EPSQ) / 127.f;
    int b = blockIdx.x >> 8;
    long px0 = (long)(blockIdx.x & 255) * 64;
    __shared__ __align__(16) i8 lj[64 * 128];
    __shared__ __align__(16) i8 li[64 * 128];
    int px = threadIdx.x & 63, cq = threadIdx.x >> 6;
    for (int it = 0; it < 8; it++) {
        int cb = it * 16 + cq * 4;
        unsigned pj = 0, pi = 0;
        #pragma unroll
        for (int e = 0; e < 4; e++) {
            int c = cb + e;
            long g = ((long)b * Cc + c) * HW + px0 + px;
            float t = t2[g], x = r1[g];
            float hq = fminf(rintf(fmaxf(t, 0.f) / s1), 255.f) * s1;
            int j = (int)fminf(fmaxf(rintf(hq / s1b), -127.f), 127.f);
            int i = (int)fminf(fmaxf(rintf(x / sx), -127.f), 127.f);
            pj |= ((unsigned)(unsigned char)(i8)j) << (8 * e);
            pi |= ((unsigned)(unsigned char)(i8)i) << (8 * e);
        }
        int ad = (px * 128 + cb) ^ ((px & 7) << 4);
        *reinterpret_cast<int*>(lj + ad) = (int)pj;
        *reinterpret_cast<int*>(li + ad) = (int)pi;
    }
    __syncthreads();
    for (int s = threadIdx.x; s < 512; s += 256) {
        int px2 = s >> 3, sl = s & 7;
        int ad = (px2 * 128 + sl * 16) ^ ((px2 & 7) << 4);
        long dst = ((long)b * HW + px0 + px2) * 128 + sl * 16;
        *reinterpret_cast<uint4v*>(jc + dst) = *reinterpret_cast<uint4v*>(lj + ad);
        *reinterpret_cast<uint4v*>(ic + dst) = *reinterpret_cast<uint4v*>(li + ad);
    }
}

// ---------------- pointwise i8-MFMA GEMM over integer codes (16x16x64) ----------------
// MODE 0: relu max only (sharded). MODE 1: write quantized i8 codes (shifted -128) NHWC.
template<int K, int OB, bool DUAL, int MODE>
__global__ __launch_bounds__(256) void pwmfma_kernel(
    const i8* __restrict__ bc0, const i8* __restrict__ bc1,
    const i8* __restrict__ wc, const float* __restrict__ bias,
    i8* __restrict__ outc, const unsigned* __restrict__ scal,
    const unsigned* __restrict__ msh, const int* __restrict__ corrI,
    int O_total, int sInSlot, int sWSlot, int sOutSlot, unsigned* moutsh) {

    constexpr int F = OB / 64;                    // o-frags (of 16) per wave
    constexpr int KB = K / 64;
    constexpr int LSZ = (DUAL ? 2 : 1) * 64 * K;
    __shared__ __align__(16) i8 lds[LSZ];
    int lane = threadIdx.x & 63, wv = threadIdx.x >> 6;
    int lane15 = lane & 15;
    int b = blockIdx.x >> 8;
    long px0 = (long)(blockIdx.x & 255) * 64;
    long pixbase = (long)b * HW + px0;
    int oB = blockIdx.y * OB;
    int oW = wv * (OB / 4);

    for (int s = threadIdx.x; s < 4 * K; s += 256) {        // 64 px * K/16 chunks
        int px = s / (K / 16), cs = s % (K / 16);
        long gsrc = (pixbase + px) * K + cs * 16;
        int addr = (px * K + cs * 16) ^ ((px & 7) << 4);
        *reinterpret_cast<uint4v*>(lds + addr) = *reinterpret_cast<const uint4v*>(bc0 + gsrc);
        if (DUAL)
            *reinterpret_cast<uint4v*>(lds + 64 * K + addr) =
                *reinterpret_cast<const uint4v*>(bc1 + gsrc);
    }
    __syncthreads();

    const int4v z4 = {0, 0, 0, 0};
    int4v accA[F][4], accB[F][4];
    #pragma unroll
    for (int i = 0; i < F; i++)
        #pragma unroll
        for (int j = 0; j < 4; j++) { accA[i][j] = z4; accB[i][j] = z4; }

    const i8* wpack = wc + ((long)((oB + oW) >> 4) * KB) * 1024 + lane * 16;

    #pragma unroll
    for (int kb = 0; kb < KB; kb++) {
        int4v a[F];
        #pragma unroll
        for (int f = 0; f < F; f++)
            a[f] = *reinterpret_cast<const int4v*>(wpack + ((long)f * KB + kb) * 1024);
        #pragma unroll
        for (int fn = 0; fn < 4; fn++) {
            int col = fn * 16 + lane15;
            int ad = (col * K + kb * 64 + (lane >> 4) * 16) ^ ((col & 7) << 4);
            int4v b0 = *reinterpret_cast<const int4v*>(lds + ad);
            #pragma unroll
            for (int f = 0; f < F; f++) accA[f][fn] = MFMAI8(a[f], b0, accA[f][fn]);
            if (DUAL) {
                int4v b1 = *reinterpret_cast<const int4v*>(lds + 64 * K + ad);
                #pragma unroll
                for (int f = 0; f < F; f++) accB[f][fn] = MFMAI8(a[f], b1, accB[f][fn]);
            }
        }
    }

    float sW = ubits(scal[sWSlot]);
    float sA, sB_;
    if (DUAL) {
        float s1 = fmaxf(rdmax16(msh + 3 * 512), EPSQ) / 255.f;
        sA  = fmaxf(255.f * s1, EPSQ) / 127.f;     // s1b (j codes)
        sB_ = fmaxf(rdmax16(msh + 2 * 512), EPSQ) / 127.f; // sx (i codes)
    } else {
        sA = fmaxf(rdmax16(msh + sInSlot * 512), EPSQ) / 255.f;
        sB_ = 0.f;
    }

    if (MODE == 0) {
        float mm = 0.f;
        #pragma unroll
        for (int f = 0; f < F; f++)
        #pragma unroll
        for (int fn = 0; fn < 4; fn++)
        #pragma unroll
        for (int r = 0; r < 4; r++) {
            int o = oB + oW + f * 16 + (lane >> 4) * 4 + r;
            float av;
            if (DUAL) av = sA * (float)accA[f][fn][r] + sB_ * (float)accB[f][fn][r];
            else      av = sA * (float)(accA[f][fn][r] + (corrI[o] << 7));
            float v = fmaxf(sW * av + bias[o], 0.f);
            mm = fmaxf(mm, v);
        }
        block_max_shard2(mm, moutsh, reinterpret_cast<float*>(lds));
    } else {
        float sOut = fmaxf(rdmax16(msh + sOutSlot * 512), EPSQ) / 255.f;
        __syncthreads();
        #pragma unroll
        for (int f = 0; f < F; f++)
        #pragma unroll
        for (int fn = 0; fn < 4; fn++) {
            int orow0 = oW + f * 16 + (lane >> 4) * 4;
            unsigned pk = 0;
            #pragma unroll
            for (int r = 0; r < 4; r++) {
                int o = oB + orow0 + r;
                float av;
                if (DUAL) av = sA * (float)accA[f][fn][r] + sB_ * (float)accB[f][fn][r];
                else      av = sA * (float)(accA[f][fn][r] + (corrI[o] << 7));
                float v = fmaxf(sW * av + bias[o], 0.f);
                int code = (int)fminf(rintf(v / sOut), 255.f) - 128;   // shifted storage
                pk |= ((unsigned)(unsigned char)(i8)code) << (8 * r);
            }
            int pxl = fn * 16 + lane15;
            int ad = (pxl * OB + orow0) ^ ((pxl & 7) << 4);
            *reinterpret_cast<int*>(lds + ad) = (int)pk;
        }
        __syncthreads();
        constexpr int CH = OB / 16;       // 16B chunks per px row
        for (int s = threadIdx.x; s < 64 * CH; s += 256) {
            int px = s / CH, sl = s % CH;
            int ad = (px * OB + sl * 16) ^ ((px & 7) << 4);
            *reinterpret_cast<uint4v*>(outc + (pixbase + px) * O_total + oB + sl * 16) =
                *reinterpret_cast<uint4v*>(lds + ad);
        }
    }
}

// ---------------- 3x3 conv 128->256, 32x32x32 i8-MFMA, fp32 NCHW out + sharded max ----------------
// Wave: 64 o x 64 px = 2x2 fragments of 32x32. A frag: o=otile*32+(lane&31),
// k=kb*32+(lane>>5)*16+e. C/D: col=lane&31, row=(reg&3)+8*(reg>>2)+4*(lane>>5).

__global__ __launch_bounds__(256) void conv3x3_mfma_kernel(
    const i8* __restrict__ xc,    // NHWC shifted codes [B*HW][128]
    const i8* __restrict__ wc,    // packed [8][9][4][64][16]
    const float* __restrict__ bias, float* __restrict__ out,
    const unsigned* __restrict__ scal, const unsigned* __restrict__ msh,
    const int* __restrict__ corrU, unsigned* moutsh) {

    __shared__ __align__(16) i8 lds[3 * 66 * 128];
    int lane = threadIdx.x & 63, wv = threadIdx.x >> 6;
    int col31 = lane & 31, khalf = lane >> 5;
    int bx = blockIdx.x;
    int b = bx >> 8, h = (bx >> 1) & 127, wseg = bx & 1;
    int oW = wv * 64;

    // stage 3 rows x 66 cols x 128 ch (i8); OOB cols = 0x80 (shifted zero)
    for (int s = threadIdx.x; s < 3 * 66 * 8; s += 256) {
        int row = s / (66 * 8), rem = s % (66 * 8), col = rem >> 3, sl = rem & 7;
        int hh = h + row - 1;
        if (hh < 0 || hh > 127) continue;      // row's taps skipped entirely
        int wgl = wseg * 64 + col - 1;
        uint4v v = {0x80808080u, 0x80808080u, 0x80808080u, 0x80808080u};
        if (wgl >= 0 && wgl <= 127) {
            long pix = (long)b * HW + (long)hh * 128 + wgl;
            v = *reinterpret_cast<const uint4v*>(xc + pix * 128 + sl * 16);
        }
        int addr = ((row * 66 + col) * 128 + sl * 16) ^ ((col & 7) << 4);
        *reinterpret_cast<uint4v*>(lds + addr) = v;
    }
    __syncthreads();

    int16v acc[2][2];                 // [o-frag][px-frag]
    #pragma unroll
    for (int f = 0; f < 2; f++)
        #pragma unroll
        for (int p = 0; p < 2; p++)
            #pragma unroll
            for (int r = 0; r < 16; r++) acc[f][p][r] = 0;

    const i8* wlane = wc + lane * 16;
    int koff = khalf * 16;
    for (int di = 0; di < 3; di++) {
        int hh = h + di - 1;
        if (hh < 0 || hh > 127) continue;      // block-uniform
        for (int dj = 0; dj < 3; dj++) {
            int tap = di * 3 + dj;
            #pragma unroll
            for (int kb = 0; kb < 4; kb++) {
                int4v a[2];
                #pragma unroll
                for (int f = 0; f < 2; f++)
                    a[f] = *reinterpret_cast<const int4v*>(
                        wlane + ((long)(((wv * 2 + f) * 9 + tap) * 4 + kb)) * 1024);
                int4v bb[2];
                #pragma unroll
                for (int p = 0; p < 2; p++) {
                    int colg = p * 32 + col31 + dj;
                    bb[p] = *reinterpret_cast<const int4v*>(lds +
                        (((di * 66 + colg) * 128 + kb * 32 + koff) ^ ((colg & 7) << 4)));
                }
                #pragma unroll
                for (int f = 0; f < 2; f++)
                    #pragma unroll
                    for (int p = 0; p < 2; p++)
                        acc[f][p] = MFMAI832(a[f], bb[p], acc[f][p]);
            }
        }
    }

    float s5 = fmaxf(rdmax16(msh + 5 * 512), EPSQ) / 255.f;
    float sc = ubits(scal[10]) * s5;
    float mm = 0.f;
    #pragma unroll
    for (int f = 0; f < 2; f++)
    #pragma unroll
    for (int r = 0; r < 16; r++) {
        int o = oW + f * 32 + (r & 3) + 8 * (r >> 2) + 4 * khalf;
        int csum = corrU[256 + o];
        if (h > 0)   csum += corrU[o];
        if (h < 127) csum += corrU[512 + o];
        #pragma unroll
        for (int p = 0; p < 2; p++) {
            int px = wseg * 64 + p * 32 + col31;
            int ai = acc[f][p][r] + (csum << 7);
            float v = fmaxf(sc * (float)ai + bias[o], 0.f);
            mm = fmaxf(mm, v);
            out[((long)(b * CO + o)) * HW + h * 128 + px] = v;
        }
    }
    block_max_shard2(mm, moutsh, reinterpret_cast<float*>(lds));
}

// ---------------- in-place quant of a relu'd tensor (255 levels) ----------------

__global__ void quant_inplace_kernel(float4* __restrict__ p, long n4,
                                     const unsigned* __restrict__ msh, int idx) {
    float s = fmaxf(rdmax16(msh + idx * 512), EPSQ) / 255.f;
    long i0 = (long)blockIdx.x * blockDim.x + threadIdx.x;
    long str = (long)gridDim.x * blockDim.x;
    for (long i = i0; i < n4; i += str) {
        float4 v = p[i];
        v.x = fminf(rintf(v.x / s), 255.f) * s;
        v.y = fminf(rintf(v.y / s), 255.f) * s;
        v.z = fminf(rintf(v.z / s), 255.f) * s;
        v.w = fminf(rintf(v.w / s), 255.f) * s;
        p[i] = v;
    }
}

// ---------------- launch ----------------

extern "C" void kernel_launch(void* const* d_in, const int* in_sizes, int n_in,
                              void* d_out, int out_size, void* d_ws, size_t ws_size,
                              hipStream_t stream) {
    (void)in_sizes; (void)n_in; (void)out_size; (void)ws_size;
    const float* x     = (const float*)d_in[0];
    const float* dw1_w = (const float*)d_in[1];
    const float* dw1_b = (const float*)d_in[2];
    const float* dw2_w = (const float*)d_in[3];
    const float* dw2_b = (const float*)d_in[4];
    const float* pw1_w = (const float*)d_in[5];
    const float* pw1_b = (const float*)d_in[6];
    const float* pw2_w = (const float*)d_in[7];
    const float* pw2_b = (const float*)d_in[8];
    const float* up_w  = (const float*)d_in[9];
    const float* up_b  = (const float*)d_in[10];
    float* out = (float*)d_out;
    float* ws  = (float*)d_ws;

    // ws layout (float units):
    // [0, NX)          Abuf fp32          (later: p1codes i8)
    // [NX, 2NX)        Bbuf fp32
    // [2NX, 2NX+NX/4)  jcode i8           (later: p2codes i8)
    // [2NX+NX/4, 2NX+NX/2) icode i8
    // [3NX, ...)       weight area + scal + corr + sharded max slots
    float* Abuf = ws;
    float* Bbuf = ws + NX;
    i8*    jcode   = (i8*)(ws + 2 * NX);
    i8*    icode   = jcode + NX;
    i8*    p1codes = (i8*)ws;
    i8*    p2codes = (i8*)(ws + 2 * NX);

    float* wbase  = ws + 3 * NX;
    float* wq_dw1 = wbase;          float* bq_dw1 = wbase + 1152;
    float* wq_dw2 = wbase + 1280;   float* bq_dw2 = wbase + 2432;
    float* bq_pw1 = wbase + 2560;
    float* bq_pw2 = wbase + 3072;
    float* bq_up  = wbase + 3200;
    i8*    wc_pw1 = (i8*)(wbase + 3456);    // 65536 B
    i8*    wc_pw2 = (i8*)(wbase + 19840);   // 65536 B
    i8*    wc_up  = (i8*)(wbase + 36224);   // 294912 B
    unsigned* scal = (unsigned*)(wbase + 109952);   // 32: weight scales + absmax
    int*   corrU  = (int*)(wbase + 109984);   // [3][256]
    int*   corrP2 = (int*)(wbase + 110752);   // [128]
    unsigned* msh = (unsigned*)(wbase + 110880); // 7 slots x 16 lines x 32 uints
    // shard slots: 0 SX | 1 M1 | 2 MR1 | 3 M2 | 4 M3(pw1 relu) | 5 M4(pw2 relu) | 6 M5(up relu)

    (void)hipMemsetAsync(scal, 0, (32 + 768 + 128 + 7 * 512) * sizeof(unsigned), stream);

    QW q0{dw1_w, wq_dw1, nullptr, 1152, 0, 0, 9},
       q1{dw1_b, bq_dw1, nullptr, 128, 0, 0, 1},
       q2{dw2_w, wq_dw2, nullptr, 1152, 0, 0, 9},
       q3{dw2_b, bq_dw2, nullptr, 128, 0, 0, 1},
       q4{pw1_w, nullptr, wc_pw1, 65536, 1, 8, 128},
       q5{pw1_b, bq_pw1, nullptr, 512, 0, 0, 1},
       q6{pw2_w, nullptr, wc_pw2, 65536, 1, 9, 512},
       q7{pw2_b, bq_pw2, nullptr, 128, 0, 0, 1},
       q8{up_w, nullptr, wc_up, 294912, 2, 10, 128},
       q9{up_b, bq_up, nullptr, 256, 0, 0, 1};
    wabsmax_kernel<<<dim3(32, 10), 256, 0, stream>>>(q0, q1, q2, q3, q4, q5, q6, q7, q8, q9, scal);
    wquant_kernel<<<dim3(32, 10), 256, 0, stream>>>(q0, q1, q2, q3, q4, q5, q6, q7, q8, q9, scal);
    corr_kernel<<<dim3(256, 2), 64, 0, stream>>>(pw2_w, up_w, scal, corrP2, corrU);

    // residual block 1 (dwconv1 also computes absmax(x) -> shard slot 0)
    dwconv_kernel<<<2048, 256, 0, stream>>>(x, wq_dw1, bq_dw1, Abuf, msh + 1 * 512, msh + 0 * 512);
    residual_kernel<<<2048, 256, 0, stream>>>((const float4*)Abuf, (const float4*)x,
                                              (float4*)Bbuf, msh, 1, 0, msh + 2 * 512);
    // residual block 2 -> i8 NHWC code planes
    dwconv_kernel<<<2048, 256, 0, stream>>>(Bbuf, wq_dw2, bq_dw2, Abuf, msh + 3 * 512, nullptr);
    residual2_codes_kernel<<<2048, 256, 0, stream>>>(Abuf, Bbuf, jcode, icode, msh);

    // pw1 (dual-plane exact GEMM): pass1 max -> shard 4, pass2 shifted codes -> p1codes
    pwmfma_kernel<128, 256, true, 0><<<dim3(2048, 2), 256, 0, stream>>>(
        jcode, icode, wc_pw1, bq_pw1, nullptr, scal, msh, nullptr, C4, 0, 8, 0, msh + 4 * 512);
    pwmfma_kernel<128, 256, true, 1><<<dim3(2048, 2), 256, 0, stream>>>(
        jcode, icode, wc_pw1, bq_pw1, p1codes, scal, msh, nullptr, C4, 0, 8, 4, nullptr);

    // pw2: shifted input (corrP2), pass1 max -> shard 5, pass2 shifted codes -> p2codes
    pwmfma_kernel<512, 128, false, 0><<<dim3(2048, 1), 256, 0, stream>>>(
        p1codes, nullptr, wc_pw2, bq_pw2, nullptr, scal, msh, corrP2, Cc, 4, 9, 0, msh + 5 * 512);
    pwmfma_kernel<512, 128, false, 1><<<dim3(2048, 1), 256, 0, stream>>>(
        p1codes, nullptr, wc_pw2, bq_pw2, p2codes, scal, msh, corrP2, Cc, 4, 9, 5, nullptr);

    // up 3x3 (32x32 MFMA) -> d_out fp32 + shard 6 max, then final quant in place
    conv3x3_mfma_kernel<<<2048, 256, 0, stream>>>(p2codes, wc_up, bq_up, out, scal, msh,
                                                  corrU, msh + 6 * 512);
    quant_inplace_kernel<<<4096, 256, 0, stream>>>((float4*)out, NOUT / 4, msh, 6);
}